// Round 1
// baseline (516.354 us; speedup 1.0000x reference)
//
#include <hip/hip_runtime.h>
#include <stdint.h>

typedef unsigned short ushort_t;
typedef __attribute__((ext_vector_type(8))) short bf16x8;   // 8 bf16 in 4 VGPRs
typedef __attribute__((ext_vector_type(4))) float f32x4;
typedef __attribute__((ext_vector_type(4))) unsigned short us4;

#define DEV __device__ __forceinline__

DEV unsigned short f2bf(float f) {           // RNE f32 -> bf16
  union { float f; unsigned u; } x; x.f = f;
  unsigned r = x.u + 0x7fffu + ((x.u >> 16) & 1u);
  return (unsigned short)(r >> 16);
}

DEV void gload16(const void* g, void* l) {   // async global->LDS, 16B/lane
  __builtin_amdgcn_global_load_lds(
      (const __attribute__((address_space(1))) unsigned int*)g,
      (__attribute__((address_space(3))) unsigned int*)l, 16, 0, 0);
}

// ---------------------------------------------------------------- casts
__global__ __launch_bounds__(256) void cast_bf16_kernel(
    const float* __restrict__ x, ushort_t* __restrict__ y, int n4) {
  int i = blockIdx.x * 256 + threadIdx.x;
  if (i >= n4) return;
  float4 v = ((const float4*)x)[i];
  us4 o; o.x = f2bf(v.x); o.y = f2bf(v.y); o.z = f2bf(v.z); o.w = f2bf(v.w);
  ((us4*)y)[i] = o;
}

// W[K,N] f32 -> Wt[N,K] bf16 (generic dims)
__global__ __launch_bounds__(256) void transpose_cast_kernel(
    const float* __restrict__ W, ushort_t* __restrict__ dst, int K, int N) {
  __shared__ float tile[64][65];
  int n0 = blockIdx.x * 64, k0 = blockIdx.y * 64;
  int tid = threadIdx.x;
#pragma unroll
  for (int it = 0; it < 16; ++it) {
    int idx = it * 256 + tid; int r = idx >> 6, c = idx & 63;
    tile[r][c] = W[(size_t)(k0 + r) * N + n0 + c];
  }
  __syncthreads();
#pragma unroll
  for (int it = 0; it < 16; ++it) {
    int idx = it * 256 + tid; int r = idx >> 6, c = idx & 63;
    dst[(size_t)(n0 + r) * K + k0 + c] = f2bf(tile[c][r]);
  }
}

struct Src8 { const float* p[8]; };
// 8x fused 1024x1024 weight transposes (one launch)
__global__ __launch_bounds__(256) void transpose_cast8_kernel(
    Src8 s, ushort_t* __restrict__ dst) {
  __shared__ float tile[64][65];
  const float* W = s.p[blockIdx.z];
  ushort_t* out = dst + (size_t)blockIdx.z * 1048576;
  int n0 = blockIdx.x * 64, k0 = blockIdx.y * 64;
  int tid = threadIdx.x;
#pragma unroll
  for (int it = 0; it < 16; ++it) {
    int idx = it * 256 + tid; int r = idx >> 6, c = idx & 63;
    tile[r][c] = W[(size_t)(k0 + r) * 1024 + n0 + c];
  }
  __syncthreads();
#pragma unroll
  for (int it = 0; it < 16; ++it) {
    int idx = it * 256 + tid; int r = idx >> 6, c = idx & 63;
    out[(size_t)(n0 + r) * 1024 + k0 + c] = f2bf(tile[c][r]);
  }
}

// V [B,S,(ldv)] head-cols -> vT [B*H, 64, 1024]
__global__ __launch_bounds__(256) void transpose_v_kernel(
    const ushort_t* __restrict__ V, int ldv, ushort_t* __restrict__ vT) {
  __shared__ ushort_t tile[64][66];
  int s0 = blockIdx.x * 64;
  int bh = blockIdx.y;
  int b = bh >> 4, h = bh & 15;
  int tid = threadIdx.x;
#pragma unroll
  for (int it = 0; it < 16; ++it) {
    int idx = it * 256 + tid; int r = idx >> 6, c = idx & 63;
    tile[r][c] = V[(size_t)(b * 1024 + s0 + r) * ldv + h * 64 + c];
  }
  __syncthreads();
#pragma unroll
  for (int it = 0; it < 16; ++it) {
    int idx = it * 256 + tid; int r = idx >> 6, c = idx & 63;
    vT[((size_t)bh * 64 + r) * 1024 + s0 + c] = tile[c][r];
  }
}

// ---------------------------------------------------------------- GEMM
// C[M,N] = A[M,K](bf16) @ Bt[N,K]^T(bf16) + bias ; m97-style 128x128 tile.
// bias pointer segmented per 1024 cols: bp[col>>10][col&1023].
template <int WF32, int WB16, int RELU>
__global__ __launch_bounds__(256, 2) void gemm_bt(
    const ushort_t* __restrict__ A, const ushort_t* __restrict__ Bt,
    const float* __restrict__ b0, const float* __restrict__ b1,
    const float* __restrict__ b2, const float* __restrict__ b3,
    float* __restrict__ Cf, ushort_t* __restrict__ Cb, int M, int N, int K) {
  __shared__ ushort_t sA[4096];  // [128][32] bf16, 8KB
  __shared__ ushort_t sB[4096];
  const int tid = threadIdx.x;
  const int w = tid >> 6, lane = tid & 63;
  const int lrow = lane & 15, lk = lane >> 4;
  const int m0 = blockIdx.x * 128, n0 = blockIdx.y * 128;
  const int wr = w >> 1, wc = w & 1;
  f32x4 acc[4][4] = {};
  const int brow0 = (w * 1024 + lane * 16) >> 6;  // row for sweep 0
  const int kbyte = (lane * 16) & 63;             // byte within 64B row

  for (int kt = 0; kt < K; kt += 32) {
    __syncthreads();
    const ushort_t* ga = A + (size_t)(m0 + brow0) * K + kt + (kbyte >> 1);
    gload16(ga, (char*)sA + w * 1024);
    gload16(ga + (size_t)64 * K, (char*)sA + 4096 + w * 1024);
    const ushort_t* gb = Bt + (size_t)(n0 + brow0) * K + kt + (kbyte >> 1);
    gload16(gb, (char*)sB + w * 1024);
    gload16(gb + (size_t)64 * K, (char*)sB + 4096 + w * 1024);
    __syncthreads();
    bf16x8 aF[4], bF[4];
#pragma unroll
    for (int t = 0; t < 4; ++t) {
      aF[t] = *(const bf16x8*)((const char*)sA + ((wr * 64 + t * 16 + lrow) << 6) + (lk << 4));
      bF[t] = *(const bf16x8*)((const char*)sB + ((wc * 64 + t * 16 + lrow) << 6) + (lk << 4));
    }
#pragma unroll
    for (int mt = 0; mt < 4; ++mt)
#pragma unroll
      for (int nt = 0; nt < 4; ++nt)
        acc[mt][nt] = __builtin_amdgcn_mfma_f32_16x16x32_bf16(aF[mt], bF[nt], acc[mt][nt], 0, 0, 0);
  }
#pragma unroll
  for (int nt = 0; nt < 4; ++nt) {
    int col = n0 + wc * 64 + nt * 16 + lrow;
    int seg = col >> 10;
    const float* bp = seg == 0 ? b0 : seg == 1 ? b1 : seg == 2 ? b2 : b3;
    float bv = bp[col & 1023];
#pragma unroll
    for (int mt = 0; mt < 4; ++mt) {
      int rowb = m0 + wr * 64 + mt * 16 + lk * 4;
#pragma unroll
      for (int j = 0; j < 4; ++j) {
        float v = acc[mt][nt][j] + bv;
        if (RELU) v = fmaxf(v, 0.f);
        size_t idx = (size_t)(rowb + j) * N + col;
        if (WF32) Cf[idx] = v;
        if (WB16) Cb[idx] = f2bf(v);
      }
    }
  }
}

// ---------------------------------------------------------------- attention
// grid (S/64, B*H). Per block: 64 q-rows, 4 waves x 16 rows. Online softmax.
template <int CAUSAL>
__global__ __launch_bounds__(256, 2) void attn_kernel(
    const ushort_t* __restrict__ Q, int ldq,
    const ushort_t* __restrict__ Kp, int ldk,
    const ushort_t* __restrict__ vT,  // [B*H,64,1024]
    const float* __restrict__ mask2,  // [B,1024] or null
    ushort_t* __restrict__ O) {       // [B*S,1024]
  __shared__ ushort_t sK[2048];       // [32 keys][64 dh]
  __shared__ ushort_t sV[2048];       // [64 dh][32 keys]
  __shared__ ushort_t sP[4][512];     // per-wave [16 q][32 keys]
  const int qb = blockIdx.x, bh = blockIdx.y;
  const int b = bh >> 4, h = bh & 15;
  const int tid = threadIdx.x, w = tid >> 6, lane = tid & 63;
  const int lrow = lane & 15, lk = lane >> 4;
  const int qrow = qb * 64 + w * 16 + lrow;
  const ushort_t* qptr = Q + (size_t)(b * 1024 + qrow) * ldq + h * 64 + lk * 8;
  bf16x8 qF0 = *(const bf16x8*)qptr;
  bf16x8 qF1 = *(const bf16x8*)(qptr + 32);
  f32x4 oacc[4] = {};
  float m_[4], l_[4];
#pragma unroll
  for (int j = 0; j < 4; ++j) { m_[j] = -3.0e38f; l_[j] = 0.f; }
  const int nkb = CAUSAL ? (qb * 2 + 2) : 32;
  const int krow = w * 8 + (lane >> 3), kcb = (lane & 7) * 16;
  const int vrow = w * 16 + (lane >> 2), vcb = (lane & 3) * 16;
  const float L2E = 1.4426950408889634f;

  for (int kb = 0; kb < nkb; ++kb) {
    __syncthreads();
    gload16(Kp + (size_t)(b * 1024 + kb * 32 + krow) * ldk + h * 64 + (kcb >> 1),
            (char*)sK + w * 1024);
    gload16(vT + ((size_t)bh * 64 + vrow) * 1024 + kb * 32 + (vcb >> 1),
            (char*)sV + w * 1024);
    __syncthreads();
    f32x4 sc0 = {}, sc1 = {};
    {
      bf16x8 k00 = *(const bf16x8*)((const char*)sK + lrow * 128 + lk * 16);
      bf16x8 k01 = *(const bf16x8*)((const char*)sK + lrow * 128 + 64 + lk * 16);
      bf16x8 k10 = *(const bf16x8*)((const char*)sK + (16 + lrow) * 128 + lk * 16);
      bf16x8 k11 = *(const bf16x8*)((const char*)sK + (16 + lrow) * 128 + 64 + lk * 16);
      sc0 = __builtin_amdgcn_mfma_f32_16x16x32_bf16(qF0, k00, sc0, 0, 0, 0);
      sc0 = __builtin_amdgcn_mfma_f32_16x16x32_bf16(qF1, k01, sc0, 0, 0, 0);
      sc1 = __builtin_amdgcn_mfma_f32_16x16x32_bf16(qF0, k10, sc1, 0, 0, 0);
      sc1 = __builtin_amdgcn_mfma_f32_16x16x32_bf16(qF1, k11, sc1, 0, 0, 0);
    }
#pragma unroll
    for (int j = 0; j < 4; ++j) {
      float s0 = sc0[j] * 0.125f;
      float s1 = sc1[j] * 0.125f;
      int k0i = kb * 32 + lrow;
      if (CAUSAL) {
        int q = qb * 64 + w * 16 + lk * 4 + j;
        if (k0i > q) s0 -= 1e9f;
        if (k0i + 16 > q) s1 -= 1e9f;
      } else {
        s0 = fmaf(mask2[b * 1024 + k0i], -1e9f, s0);
        s1 = fmaf(mask2[b * 1024 + k0i + 16], -1e9f, s1);
      }
      float mx = fmaxf(s0, s1);
      mx = fmaxf(mx, __shfl_xor(mx, 1));
      mx = fmaxf(mx, __shfl_xor(mx, 2));
      mx = fmaxf(mx, __shfl_xor(mx, 4));
      mx = fmaxf(mx, __shfl_xor(mx, 8));
      float mnew = fmaxf(m_[j], mx);
      float scale = __builtin_exp2f((m_[j] - mnew) * L2E);
      float e0 = __builtin_exp2f((s0 - mnew) * L2E);
      float e1 = __builtin_exp2f((s1 - mnew) * L2E);
      float ps = e0 + e1;
      ps += __shfl_xor(ps, 1);
      ps += __shfl_xor(ps, 2);
      ps += __shfl_xor(ps, 4);
      ps += __shfl_xor(ps, 8);
      l_[j] = l_[j] * scale + ps;
      m_[j] = mnew;
#pragma unroll
      for (int t = 0; t < 4; ++t) oacc[t][j] *= scale;
      sP[w][(lk * 4 + j) * 32 + lrow] = f2bf(e0);
      sP[w][(lk * 4 + j) * 32 + lrow + 16] = f2bf(e1);
    }
    __syncthreads();
    bf16x8 pF = *(const bf16x8*)((const char*)&sP[w][0] + lrow * 64 + lk * 16);
#pragma unroll
    for (int t = 0; t < 4; ++t) {
      bf16x8 vF = *(const bf16x8*)((const char*)sV + (t * 16 + lrow) * 64 + lk * 16);
      oacc[t] = __builtin_amdgcn_mfma_f32_16x16x32_bf16(pF, vF, oacc[t], 0, 0, 0);
    }
  }
#pragma unroll
  for (int j = 0; j < 4; ++j) {
    float invl = 1.f / l_[j];
    int row = qb * 64 + w * 16 + lk * 4 + j;
    ushort_t* op = O + (size_t)(b * 1024 + row) * 1024 + h * 64;
#pragma unroll
    for (int t = 0; t < 4; ++t) op[t * 16 + lrow] = f2bf(oacc[t][j] * invl);
  }
}

// ---------------------------------------------------------------- layernorm
// y = LN(a_row + r_row) * g + beta ; writes f32 (yf) and optionally bf16 (yb)
template <int WB16>
__global__ __launch_bounds__(256) void ln_kernel(
    const float* __restrict__ a, const float* __restrict__ r,
    const float* __restrict__ g, const float* __restrict__ be,
    float* __restrict__ yf, ushort_t* __restrict__ yb) {
  int row = blockIdx.x, tid = threadIdx.x;
  float4 va = ((const float4*)(a + (size_t)row * 1024))[tid];
  float4 vb = ((const float4*)(r + (size_t)row * 1024))[tid];
  float x0 = va.x + vb.x, x1 = va.y + vb.y, x2 = va.z + vb.z, x3 = va.w + vb.w;
  float s = x0 + x1 + x2 + x3;
  float s2 = x0 * x0 + x1 * x1 + x2 * x2 + x3 * x3;
#pragma unroll
  for (int o = 1; o < 64; o <<= 1) { s += __shfl_xor(s, o); s2 += __shfl_xor(s2, o); }
  __shared__ float sh[8];
  if ((tid & 63) == 0) { sh[tid >> 6] = s; sh[4 + (tid >> 6)] = s2; }
  __syncthreads();
  s = sh[0] + sh[1] + sh[2] + sh[3];
  s2 = sh[4] + sh[5] + sh[6] + sh[7];
  float mu = s * 0.0009765625f;
  float var = s2 * 0.0009765625f - mu * mu;
  float inv = rsqrtf(var + 1e-6f);
  float4 gv = ((const float4*)g)[tid];
  float4 bv = ((const float4*)be)[tid];
  float y0 = (x0 - mu) * inv * gv.x + bv.x;
  float y1 = (x1 - mu) * inv * gv.y + bv.y;
  float y2 = (x2 - mu) * inv * gv.z + bv.z;
  float y3 = (x3 - mu) * inv * gv.w + bv.w;
  ((float4*)(yf + (size_t)row * 1024))[tid] = make_float4(y0, y1, y2, y3);
  if (WB16) {
    us4 o; o.x = f2bf(y0); o.y = f2bf(y1); o.z = f2bf(y2); o.w = f2bf(y3);
    ((us4*)(yb + (size_t)row * 1024))[tid] = o;
  }
}

// ---------------------------------------------------------------- launcher
extern "C" void kernel_launch(void* const* d_in, const int* in_sizes, int n_in,
                              void* d_out, int out_size, void* d_ws, size_t ws_size,
                              hipStream_t stream) {
  (void)in_sizes; (void)n_in; (void)out_size; (void)ws_size;
  const float* inputs = (const float*)d_in[0];
  const float* enc    = (const float*)d_in[1];
  const float* mask2  = (const float*)d_in[3];
  const float* wq1 = (const float*)d_in[4];  const float* bq1 = (const float*)d_in[5];
  const float* wk1 = (const float*)d_in[6];  const float* bk1 = (const float*)d_in[7];
  const float* wv1 = (const float*)d_in[8];  const float* bv1 = (const float*)d_in[9];
  const float* wo1 = (const float*)d_in[10]; const float* bo1 = (const float*)d_in[11];
  const float* wq2 = (const float*)d_in[12]; const float* bq2 = (const float*)d_in[13];
  const float* wk2 = (const float*)d_in[14]; const float* bk2 = (const float*)d_in[15];
  const float* wv2 = (const float*)d_in[16]; const float* bv2 = (const float*)d_in[17];
  const float* wo2 = (const float*)d_in[18]; const float* bo2 = (const float*)d_in[19];
  const float* wff1 = (const float*)d_in[20]; const float* bff1 = (const float*)d_in[21];
  const float* wff2 = (const float*)d_in[22]; const float* bff2 = (const float*)d_in[23];
  const float* g1 = (const float*)d_in[24]; const float* be1 = (const float*)d_in[25];
  const float* g2 = (const float*)d_in[26]; const float* be2 = (const float*)d_in[27];
  const float* g3 = (const float*)d_in[28]; const float* be3 = (const float*)d_in[29];

  char* ws = (char*)d_ws;
  const size_t MB = 1024 * 1024;
  const size_t W1M = 1048576;  // elements per 1024x1024 weight
  ushort_t* wt    = (ushort_t*)ws;              // 0..32MB transposed bf16 weights
  ushort_t* xb    = (ushort_t*)(ws + 32 * MB);  // 8MB
  ushort_t* encb  = (ushort_t*)(ws + 40 * MB);  // 8MB
  ushort_t* qkvb  = (ushort_t*)(ws + 48 * MB);  // 24MB [4096][3072]
  ushort_t* q2b   = (ushort_t*)(ws + 48 * MB);  // reuse after attn1
  ushort_t* kv2b  = (ushort_t*)(ws + 56 * MB);  // 16MB [4096][2048]
  ushort_t* vtb   = (ushort_t*)(ws + 72 * MB);  // 8MB
  ushort_t* attnb = (ushort_t*)(ws + 80 * MB);  // 8MB
  ushort_t* y1b   = (ushort_t*)(ws + 88 * MB);  // 8MB
  ushort_t* y2b   = (ushort_t*)(ws + 96 * MB);  // 8MB
  float* c1f = (float*)(ws + 104 * MB);         // 16MB
  float* y1f = (float*)(ws + 120 * MB);         // 16MB
  float* y2f = (float*)(ws + 136 * MB);         // 16MB
  ushort_t* hb = (ushort_t*)(ws + 32 * MB);     // 32MB FFN hidden (overlays dead bufs)
  float* outf = (float*)d_out;

  // prep: casts + weight transposes
  cast_bf16_kernel<<<4096, 256, 0, stream>>>(inputs, xb, 1048576);
  cast_bf16_kernel<<<4096, 256, 0, stream>>>(enc, encb, 1048576);
  Src8 s8; s8.p[0] = wq1; s8.p[1] = wk1; s8.p[2] = wv1; s8.p[3] = wo1;
           s8.p[4] = wq2; s8.p[5] = wk2; s8.p[6] = wv2; s8.p[7] = wo2;
  transpose_cast8_kernel<<<dim3(16, 16, 8), 256, 0, stream>>>(s8, wt);
  transpose_cast_kernel<<<dim3(64, 16), 256, 0, stream>>>(wff1, wt + 8 * W1M, 1024, 4096);
  transpose_cast_kernel<<<dim3(16, 64), 256, 0, stream>>>(wff2, wt + 12 * W1M, 4096, 1024);

  // ---- self-attention
  gemm_bt<0, 1, 0><<<dim3(32, 24), 256, 0, stream>>>(
      xb, wt, bq1, bk1, bv1, bv1, nullptr, qkvb, 4096, 3072, 1024);
  transpose_v_kernel<<<dim3(16, 64), 256, 0, stream>>>(qkvb + 2048, 3072, vtb);
  attn_kernel<1><<<dim3(16, 64), 256, 0, stream>>>(
      qkvb, 3072, qkvb + 1024, 3072, vtb, nullptr, attnb);
  gemm_bt<1, 0, 0><<<dim3(32, 8), 256, 0, stream>>>(
      attnb, wt + 3 * W1M, bo1, bo1, bo1, bo1, c1f, nullptr, 4096, 1024, 1024);
  ln_kernel<1><<<4096, 256, 0, stream>>>(c1f, inputs, g1, be1, y1f, y1b);

  // ---- cross-attention
  gemm_bt<0, 1, 0><<<dim3(32, 8), 256, 0, stream>>>(
      y1b, wt + 4 * W1M, bq2, bq2, bq2, bq2, nullptr, q2b, 4096, 1024, 1024);
  gemm_bt<0, 1, 0><<<dim3(32, 16), 256, 0, stream>>>(
      encb, wt + 5 * W1M, bk2, bv2, bk2, bk2, nullptr, kv2b, 4096, 2048, 1024);
  transpose_v_kernel<<<dim3(16, 64), 256, 0, stream>>>(kv2b + 1024, 2048, vtb);
  attn_kernel<0><<<dim3(16, 64), 256, 0, stream>>>(
      q2b, 1024, kv2b, 2048, vtb, mask2, attnb);
  gemm_bt<1, 0, 0><<<dim3(32, 8), 256, 0, stream>>>(
      attnb, wt + 7 * W1M, bo2, bo2, bo2, bo2, c1f, nullptr, 4096, 1024, 1024);
  ln_kernel<1><<<4096, 256, 0, stream>>>(c1f, y1f, g2, be2, y2f, y2b);

  // ---- FFN
  gemm_bt<0, 1, 1><<<dim3(32, 32), 256, 0, stream>>>(
      y2b, wt + 8 * W1M, bff1, bff1 + 1024, bff1 + 2048, bff1 + 3072,
      nullptr, hb, 4096, 4096, 1024);
  gemm_bt<1, 0, 0><<<dim3(32, 8), 256, 0, stream>>>(
      hb, wt + 12 * W1M, bff2, bff2, bff2, bff2, c1f, nullptr, 4096, 1024, 4096);
  ln_kernel<0><<<4096, 256, 0, stream>>>(c1f, y2f, g3, be3, outf, nullptr);
}

// Round 2
// 449.147 us; speedup vs baseline: 1.1496x; 1.1496x over previous
//
#include <hip/hip_runtime.h>
#include <stdint.h>

typedef unsigned short ushort_t;
typedef __attribute__((ext_vector_type(8))) short bf16x8;   // 8 bf16 in 4 VGPRs
typedef __attribute__((ext_vector_type(4))) float f32x4;
typedef __attribute__((ext_vector_type(4))) unsigned short us4;

#define DEV __device__ __forceinline__

DEV unsigned short f2bf(float f) {           // RNE f32 -> bf16
  union { float f; unsigned u; } x; x.f = f;
  unsigned r = x.u + 0x7fffu + ((x.u >> 16) & 1u);
  return (unsigned short)(r >> 16);
}

DEV void gload16(const void* g, void* l) {   // async global->LDS, 16B/lane
  __builtin_amdgcn_global_load_lds(
      (const __attribute__((address_space(1))) unsigned int*)g,
      (__attribute__((address_space(3))) unsigned int*)l, 16, 0, 0);
}

// ---------------------------------------------------------------- casts
__global__ __launch_bounds__(256) void cast_bf16_kernel(
    const float* __restrict__ x, ushort_t* __restrict__ y, int n4) {
  int i = blockIdx.x * 256 + threadIdx.x;
  if (i >= n4) return;
  float4 v = ((const float4*)x)[i];
  us4 o; o.x = f2bf(v.x); o.y = f2bf(v.y); o.z = f2bf(v.z); o.w = f2bf(v.w);
  ((us4*)y)[i] = o;
}

// W[K,N] f32 -> Wt[N,K] bf16 (generic dims)
__global__ __launch_bounds__(256) void transpose_cast_kernel(
    const float* __restrict__ W, ushort_t* __restrict__ dst, int K, int N) {
  __shared__ float tile[64][65];
  int n0 = blockIdx.x * 64, k0 = blockIdx.y * 64;
  int tid = threadIdx.x;
#pragma unroll
  for (int it = 0; it < 16; ++it) {
    int idx = it * 256 + tid; int r = idx >> 6, c = idx & 63;
    tile[r][c] = W[(size_t)(k0 + r) * N + n0 + c];
  }
  __syncthreads();
#pragma unroll
  for (int it = 0; it < 16; ++it) {
    int idx = it * 256 + tid; int r = idx >> 6, c = idx & 63;
    dst[(size_t)(n0 + r) * K + k0 + c] = f2bf(tile[c][r]);
  }
}

struct Src8 { const float* p[8]; };
// 8x fused 1024x1024 weight transposes (one launch)
__global__ __launch_bounds__(256) void transpose_cast8_kernel(
    Src8 s, ushort_t* __restrict__ dst) {
  __shared__ float tile[64][65];
  const float* W = s.p[blockIdx.z];
  ushort_t* out = dst + (size_t)blockIdx.z * 1048576;
  int n0 = blockIdx.x * 64, k0 = blockIdx.y * 64;
  int tid = threadIdx.x;
#pragma unroll
  for (int it = 0; it < 16; ++it) {
    int idx = it * 256 + tid; int r = idx >> 6, c = idx & 63;
    tile[r][c] = W[(size_t)(k0 + r) * 1024 + n0 + c];
  }
  __syncthreads();
#pragma unroll
  for (int it = 0; it < 16; ++it) {
    int idx = it * 256 + tid; int r = idx >> 6, c = idx & 63;
    out[(size_t)(n0 + r) * 1024 + k0 + c] = f2bf(tile[c][r]);
  }
}

// V [B,S,(ldv)] head-cols -> vT [B*H, 64, 1024]   (us4-vectorized global I/O)
__global__ __launch_bounds__(256) void transpose_v_kernel(
    const ushort_t* __restrict__ V, int ldv, ushort_t* __restrict__ vT) {
  __shared__ ushort_t tile[64][65];
  int s0 = blockIdx.x * 64;
  int bh = blockIdx.y;
  int b = bh >> 4, h = bh & 15;
  int tid = threadIdx.x;
#pragma unroll
  for (int it = 0; it < 4; ++it) {
    int idx = it * 256 + tid; int r = idx >> 4, c = (idx & 15) * 4;
    us4 v = *(const us4*)&V[(size_t)(b * 1024 + s0 + r) * ldv + h * 64 + c];
    tile[r][c] = v.x; tile[r][c + 1] = v.y; tile[r][c + 2] = v.z; tile[r][c + 3] = v.w;
  }
  __syncthreads();
#pragma unroll
  for (int it = 0; it < 4; ++it) {
    int idx = it * 256 + tid; int r = idx >> 4, c = (idx & 15) * 4;
    us4 o; o.x = tile[c][r]; o.y = tile[c + 1][r]; o.z = tile[c + 2][r]; o.w = tile[c + 3][r];
    *(us4*)&vT[((size_t)bh * 64 + r) * 1024 + s0 + c] = o;
  }
}

// ---------------------------------------------------------------- GEMM
// C[M,N] = A[M,K](bf16) @ Bt[N,K]^T(bf16) + bias ; m97-style 128x128 tile.
template <int WF32, int WB16, int RELU>
__global__ __launch_bounds__(256, 2) void gemm_bt(
    const ushort_t* __restrict__ A, const ushort_t* __restrict__ Bt,
    const float* __restrict__ b0, const float* __restrict__ b1,
    const float* __restrict__ b2, const float* __restrict__ b3,
    float* __restrict__ Cf, ushort_t* __restrict__ Cb, int M, int N, int K) {
  __shared__ ushort_t sA[4096];  // [128][32] bf16, 8KB
  __shared__ ushort_t sB[4096];
  const int tid = threadIdx.x;
  const int w = tid >> 6, lane = tid & 63;
  const int lrow = lane & 15, lk = lane >> 4;
  const int m0 = blockIdx.x * 128, n0 = blockIdx.y * 128;
  const int wr = w >> 1, wc = w & 1;
  f32x4 acc[4][4] = {};
  const int brow0 = (w * 1024 + lane * 16) >> 6;  // row for sweep 0
  const int kbyte = (lane * 16) & 63;             // byte within 64B row

  for (int kt = 0; kt < K; kt += 32) {
    __syncthreads();
    const ushort_t* ga = A + (size_t)(m0 + brow0) * K + kt + (kbyte >> 1);
    gload16(ga, (char*)sA + w * 1024);
    gload16(ga + (size_t)64 * K, (char*)sA + 4096 + w * 1024);
    const ushort_t* gb = Bt + (size_t)(n0 + brow0) * K + kt + (kbyte >> 1);
    gload16(gb, (char*)sB + w * 1024);
    gload16(gb + (size_t)64 * K, (char*)sB + 4096 + w * 1024);
    __syncthreads();
    bf16x8 aF[4], bF[4];
#pragma unroll
    for (int t = 0; t < 4; ++t) {
      aF[t] = *(const bf16x8*)((const char*)sA + ((wr * 64 + t * 16 + lrow) << 6) + (lk << 4));
      bF[t] = *(const bf16x8*)((const char*)sB + ((wc * 64 + t * 16 + lrow) << 6) + (lk << 4));
    }
#pragma unroll
    for (int mt = 0; mt < 4; ++mt)
#pragma unroll
      for (int nt = 0; nt < 4; ++nt)
        acc[mt][nt] = __builtin_amdgcn_mfma_f32_16x16x32_bf16(aF[mt], bF[nt], acc[mt][nt], 0, 0, 0);
  }
#pragma unroll
  for (int nt = 0; nt < 4; ++nt) {
    int col = n0 + wc * 64 + nt * 16 + lrow;
    int seg = col >> 10;
    const float* bp = seg == 0 ? b0 : seg == 1 ? b1 : seg == 2 ? b2 : b3;
    float bv = bp[col & 1023];
#pragma unroll
    for (int mt = 0; mt < 4; ++mt) {
      int rowb = m0 + wr * 64 + mt * 16 + lk * 4;
#pragma unroll
      for (int j = 0; j < 4; ++j) {
        float v = acc[mt][nt][j] + bv;
        if (RELU) v = fmaxf(v, 0.f);
        size_t idx = (size_t)(rowb + j) * N + col;
        if (WF32) Cf[idx] = v;
        if (WB16) Cb[idx] = f2bf(v);
      }
    }
  }
}

// ---------------------------------------------------------------- attention
// grid (S/64, B*H). 64 q rows/block, 4 waves x 16 rows. KVBLK=64,
// double-buffered K/V staging (T3 2-phase), XOR-swizzled LDS tiles.
// Raw-score softmax: 1/8 scale folded into exp2 constant.
template <int CAUSAL>
__global__ __launch_bounds__(256, 4) void attn_kernel(
    const ushort_t* __restrict__ Q, int ldq,
    const ushort_t* __restrict__ Kp, int ldk,
    const ushort_t* __restrict__ vT,  // [B*H,64,1024]
    const float* __restrict__ mask2,  // [B,1024] or null
    ushort_t* __restrict__ O) {       // [B*S,1024]
  __shared__ ushort_t sK[2][4096];    // [64 key][64 dh] swizzled, 8KB each
  __shared__ ushort_t sV[2][4096];    // [64 dh][64 key] swizzled
  __shared__ ushort_t sP[4][1024];    // per-wave [16 q][64 key] swizzled
  const int qb = blockIdx.x, bh = blockIdx.y;
  const int b = bh >> 4, h = bh & 15;
  const int tid = threadIdx.x, w = tid >> 6, lane = tid & 63;
  const int lrow = lane & 15, lk = lane >> 4;

  const ushort_t* qptr = Q + (size_t)(b * 1024 + qb * 64 + w * 16 + lrow) * ldq + h * 64 + lk * 8;
  bf16x8 qF0 = *(const bf16x8*)qptr;
  bf16x8 qF1 = *(const bf16x8*)(qptr + 32);
  f32x4 oacc[4] = {};
  float m_[4], l_[4];
#pragma unroll
  for (int j = 0; j < 4; ++j) { m_[j] = -3.0e38f; l_[j] = 0.f; }
  const int nkb = CAUSAL ? (qb + 1) : 16;
  const float C = 0.18033688011112042f;  // 0.125 * log2(e)

  // staging geometry: lane covers row sr (+8 for 2nd gload), source col
  // pre-swizzled so linear LDS dest == swizzled tile (rule 21).
  const int sr = w * 16 + (lane >> 3);                  // row within 64
  const int scb = (((lane & 7) ^ (lane >> 3)) * 16);    // swizzled col byte
  const ushort_t* kbase = Kp + (size_t)(b * 1024 + sr) * ldk + h * 64 + (scb >> 1);
  const ushort_t* vbase = vT + ((size_t)bh * 64 + sr) * 1024 + (scb >> 1);
  char* dstK0 = (char*)sK[0] + w * 2048;  // HW adds lane*16
  char* dstV0 = (char*)sV[0] + w * 2048;

#define STAGE(kb_, bufi)                                              \
  do {                                                                \
    const ushort_t* gk = kbase + (size_t)(kb_) * 64 * ldk;            \
    gload16(gk, dstK0 + (bufi) * 8192);                               \
    gload16(gk + (size_t)8 * ldk, dstK0 + (bufi) * 8192 + 1024);      \
    const ushort_t* gv = vbase + (kb_) * 64;                          \
    gload16(gv, dstV0 + (bufi) * 8192);                               \
    gload16(gv + (size_t)8 * 1024, dstV0 + (bufi) * 8192 + 1024);     \
  } while (0)

  STAGE(0, 0);
  const int swz = (lrow & 7) << 4;

  for (int kb = 0; kb < nkb; ++kb) {
    const int buf = kb & 1;
    __syncthreads();                       // drains vmcnt: buf ready, buf^1 free
    if (kb + 1 < nkb) STAGE(kb + 1, buf ^ 1);

    const char* kB = (const char*)sK[buf];
    const char* vB = (const char*)sV[buf];
    // ---- QK^T (raw scores)
    f32x4 sc[4];
#pragma unroll
    for (int kt = 0; kt < 4; ++kt) {
      const char* rp = kB + ((kt * 16 + lrow) << 7);
      bf16x8 k0 = *(const bf16x8*)(rp + ((lk * 16) ^ swz));
      bf16x8 k1 = *(const bf16x8*)(rp + ((64 + lk * 16) ^ swz));
      f32x4 z = {};
      z = __builtin_amdgcn_mfma_f32_16x16x32_bf16(qF0, k0, z, 0, 0, 0);
      sc[kt] = __builtin_amdgcn_mfma_f32_16x16x32_bf16(qF1, k1, z, 0, 0, 0);
    }
    // ---- mask + online softmax (per q row j)
    float mv[4];
    if (!CAUSAL) {
#pragma unroll
      for (int kt = 0; kt < 4; ++kt)
        mv[kt] = mask2[b * 1024 + kb * 64 + kt * 16 + lrow];
    }
#pragma unroll
    for (int j = 0; j < 4; ++j) {
      float s0 = sc[0][j], s1 = sc[1][j], s2 = sc[2][j], s3 = sc[3][j];
      if (CAUSAL) {
        if (kb == qb) {
          int qr = w * 16 + lk * 4 + j;
          if (lrow > qr) s0 = -3.0e38f;
          if (16 + lrow > qr) s1 = -3.0e38f;
          if (32 + lrow > qr) s2 = -3.0e38f;
          if (48 + lrow > qr) s3 = -3.0e38f;
        }
      } else {
        s0 = fmaf(mv[0], -8e9f, s0);
        s1 = fmaf(mv[1], -8e9f, s1);
        s2 = fmaf(mv[2], -8e9f, s2);
        s3 = fmaf(mv[3], -8e9f, s3);
      }
      float mx = fmaxf(fmaxf(s0, s1), fmaxf(s2, s3));
      mx = fmaxf(mx, __shfl_xor(mx, 1));
      mx = fmaxf(mx, __shfl_xor(mx, 2));
      mx = fmaxf(mx, __shfl_xor(mx, 4));
      mx = fmaxf(mx, __shfl_xor(mx, 8));
      float mnew = fmaxf(m_[j], mx);
      float scale = __builtin_exp2f((m_[j] - mnew) * C);
      float e0 = __builtin_exp2f((s0 - mnew) * C);
      float e1 = __builtin_exp2f((s1 - mnew) * C);
      float e2 = __builtin_exp2f((s2 - mnew) * C);
      float e3 = __builtin_exp2f((s3 - mnew) * C);
      float ps = (e0 + e1) + (e2 + e3);
      ps += __shfl_xor(ps, 1);
      ps += __shfl_xor(ps, 2);
      ps += __shfl_xor(ps, 4);
      ps += __shfl_xor(ps, 8);
      l_[j] = l_[j] * scale + ps;
      m_[j] = mnew;
      oacc[0][j] *= scale; oacc[1][j] *= scale;
      oacc[2][j] *= scale; oacc[3][j] *= scale;
      // P write (wave-local LDS, swizzled by q row)
      int qp = lk * 4 + j;
      char* bp = (char*)sP[w] + qp * 128;
      int sz = (qp & 7) << 4;
      *(ushort_t*)(bp + ((lrow * 2) ^ sz)) = f2bf(e0);
      *(ushort_t*)(bp + ((32 + lrow * 2) ^ sz)) = f2bf(e1);
      *(ushort_t*)(bp + ((64 + lrow * 2) ^ sz)) = f2bf(e2);
      *(ushort_t*)(bp + ((96 + lrow * 2) ^ sz)) = f2bf(e3);
    }
    // ---- PV (wave-local dependency; compiler inserts lgkmcnt wait)
    const char* pB = (const char*)sP[w] + (lrow << 7);
    bf16x8 pF0 = *(const bf16x8*)(pB + ((lk * 16) ^ swz));
    bf16x8 pF1 = *(const bf16x8*)(pB + ((64 + lk * 16) ^ swz));
#pragma unroll
    for (int t = 0; t < 4; ++t) {
      const char* rp = vB + ((t * 16 + lrow) << 7);
      bf16x8 v0 = *(const bf16x8*)(rp + ((lk * 16) ^ swz));
      bf16x8 v1 = *(const bf16x8*)(rp + ((64 + lk * 16) ^ swz));
      oacc[t] = __builtin_amdgcn_mfma_f32_16x16x32_bf16(pF0, v0, oacc[t], 0, 0, 0);
      oacc[t] = __builtin_amdgcn_mfma_f32_16x16x32_bf16(pF1, v1, oacc[t], 0, 0, 0);
    }
  }
#undef STAGE
#pragma unroll
  for (int j = 0; j < 4; ++j) {
    float invl = 1.f / l_[j];
    int row = qb * 64 + w * 16 + lk * 4 + j;
    ushort_t* op = O + (size_t)(b * 1024 + row) * 1024 + h * 64;
#pragma unroll
    for (int t = 0; t < 4; ++t) op[t * 16 + lrow] = f2bf(oacc[t][j] * invl);
  }
}

// ---------------------------------------------------------------- layernorm
// y = LN(a_row + r_row) * g + beta ; writes f32 (yf) and optionally bf16 (yb)
template <int WB16>
__global__ __launch_bounds__(256) void ln_kernel(
    const float* __restrict__ a, const float* __restrict__ r,
    const float* __restrict__ g, const float* __restrict__ be,
    float* __restrict__ yf, ushort_t* __restrict__ yb) {
  int row = blockIdx.x, tid = threadIdx.x;
  float4 va = ((const float4*)(a + (size_t)row * 1024))[tid];
  float4 vb = ((const float4*)(r + (size_t)row * 1024))[tid];
  float x0 = va.x + vb.x, x1 = va.y + vb.y, x2 = va.z + vb.z, x3 = va.w + vb.w;
  float s = x0 + x1 + x2 + x3;
  float s2 = x0 * x0 + x1 * x1 + x2 * x2 + x3 * x3;
#pragma unroll
  for (int o = 1; o < 64; o <<= 1) { s += __shfl_xor(s, o); s2 += __shfl_xor(s2, o); }
  __shared__ float sh[8];
  if ((tid & 63) == 0) { sh[tid >> 6] = s; sh[4 + (tid >> 6)] = s2; }
  __syncthreads();
  s = sh[0] + sh[1] + sh[2] + sh[3];
  s2 = sh[4] + sh[5] + sh[6] + sh[7];
  float mu = s * 0.0009765625f;
  float var = s2 * 0.0009765625f - mu * mu;
  float inv = rsqrtf(var + 1e-6f);
  float4 gv = ((const float4*)g)[tid];
  float4 bv = ((const float4*)be)[tid];
  float y0 = (x0 - mu) * inv * gv.x + bv.x;
  float y1 = (x1 - mu) * inv * gv.y + bv.y;
  float y2 = (x2 - mu) * inv * gv.z + bv.z;
  float y3 = (x3 - mu) * inv * gv.w + bv.w;
  ((float4*)(yf + (size_t)row * 1024))[tid] = make_float4(y0, y1, y2, y3);
  if (WB16) {
    us4 o; o.x = f2bf(y0); o.y = f2bf(y1); o.z = f2bf(y2); o.w = f2bf(y3);
    ((us4*)(yb + (size_t)row * 1024))[tid] = o;
  }
}

// ---------------------------------------------------------------- launcher
extern "C" void kernel_launch(void* const* d_in, const int* in_sizes, int n_in,
                              void* d_out, int out_size, void* d_ws, size_t ws_size,
                              hipStream_t stream) {
  (void)in_sizes; (void)n_in; (void)out_size; (void)ws_size;
  const float* inputs = (const float*)d_in[0];
  const float* enc    = (const float*)d_in[1];
  const float* mask2  = (const float*)d_in[3];
  const float* wq1 = (const float*)d_in[4];  const float* bq1 = (const float*)d_in[5];
  const float* wk1 = (const float*)d_in[6];  const float* bk1 = (const float*)d_in[7];
  const float* wv1 = (const float*)d_in[8];  const float* bv1 = (const float*)d_in[9];
  const float* wo1 = (const float*)d_in[10]; const float* bo1 = (const float*)d_in[11];
  const float* wq2 = (const float*)d_in[12]; const float* bq2 = (const float*)d_in[13];
  const float* wk2 = (const float*)d_in[14]; const float* bk2 = (const float*)d_in[15];
  const float* wv2 = (const float*)d_in[16]; const float* bv2 = (const float*)d_in[17];
  const float* wo2 = (const float*)d_in[18]; const float* bo2 = (const float*)d_in[19];
  const float* wff1 = (const float*)d_in[20]; const float* bff1 = (const float*)d_in[21];
  const float* wff2 = (const float*)d_in[22]; const float* bff2 = (const float*)d_in[23];
  const float* g1 = (const float*)d_in[24]; const float* be1 = (const float*)d_in[25];
  const float* g2 = (const float*)d_in[26]; const float* be2 = (const float*)d_in[27];
  const float* g3 = (const float*)d_in[28]; const float* be3 = (const float*)d_in[29];

  char* ws = (char*)d_ws;
  const size_t MB = 1024 * 1024;
  const size_t W1M = 1048576;  // elements per 1024x1024 weight
  ushort_t* wt    = (ushort_t*)ws;              // 0..32MB transposed bf16 weights
  ushort_t* xb    = (ushort_t*)(ws + 32 * MB);  // 8MB
  ushort_t* encb  = (ushort_t*)(ws + 40 * MB);  // 8MB
  ushort_t* qkvb  = (ushort_t*)(ws + 48 * MB);  // 24MB [4096][3072]
  ushort_t* q2b   = (ushort_t*)(ws + 48 * MB);  // reuse after attn1
  ushort_t* kv2b  = (ushort_t*)(ws + 56 * MB);  // 16MB [4096][2048]
  ushort_t* vtb   = (ushort_t*)(ws + 72 * MB);  // 8MB
  ushort_t* attnb = (ushort_t*)(ws + 80 * MB);  // 8MB
  ushort_t* y1b   = (ushort_t*)(ws + 88 * MB);  // 8MB
  ushort_t* y2b   = (ushort_t*)(ws + 96 * MB);  // 8MB
  float* c1f = (float*)(ws + 104 * MB);         // 16MB
  float* y1f = (float*)(ws + 120 * MB);         // 16MB
  float* y2f = (float*)(ws + 136 * MB);         // 16MB
  ushort_t* hb = (ushort_t*)(ws + 32 * MB);     // 32MB FFN hidden (overlays dead bufs)
  float* outf = (float*)d_out;

  // prep: casts + weight transposes
  cast_bf16_kernel<<<4096, 256, 0, stream>>>(inputs, xb, 1048576);
  cast_bf16_kernel<<<4096, 256, 0, stream>>>(enc, encb, 1048576);
  Src8 s8; s8.p[0] = wq1; s8.p[1] = wk1; s8.p[2] = wv1; s8.p[3] = wo1;
           s8.p[4] = wq2; s8.p[5] = wk2; s8.p[6] = wv2; s8.p[7] = wo2;
  transpose_cast8_kernel<<<dim3(16, 16, 8), 256, 0, stream>>>(s8, wt);
  transpose_cast_kernel<<<dim3(64, 16), 256, 0, stream>>>(wff1, wt + 8 * W1M, 1024, 4096);
  transpose_cast_kernel<<<dim3(16, 64), 256, 0, stream>>>(wff2, wt + 12 * W1M, 4096, 1024);

  // ---- self-attention
  gemm_bt<0, 1, 0><<<dim3(32, 24), 256, 0, stream>>>(
      xb, wt, bq1, bk1, bv1, bv1, nullptr, qkvb, 4096, 3072, 1024);
  transpose_v_kernel<<<dim3(16, 64), 256, 0, stream>>>(qkvb + 2048, 3072, vtb);
  attn_kernel<1><<<dim3(16, 64), 256, 0, stream>>>(
      qkvb, 3072, qkvb + 1024, 3072, vtb, nullptr, attnb);
  gemm_bt<1, 0, 0><<<dim3(32, 8), 256, 0, stream>>>(
      attnb, wt + 3 * W1M, bo1, bo1, bo1, bo1, c1f, nullptr, 4096, 1024, 1024);
  ln_kernel<1><<<4096, 256, 0, stream>>>(c1f, inputs, g1, be1, y1f, y1b);

  // ---- cross-attention
  gemm_bt<0, 1, 0><<<dim3(32, 8), 256, 0, stream>>>(
      y1b, wt + 4 * W1M, bq2, bq2, bq2, bq2, nullptr, q2b, 4096, 1024, 1024);
  gemm_bt<0, 1, 0><<<dim3(32, 16), 256, 0, stream>>>(
      encb, wt + 5 * W1M, bk2, bv2, bk2, bk2, nullptr, kv2b, 4096, 2048, 1024);
  transpose_v_kernel<<<dim3(16, 64), 256, 0, stream>>>(kv2b + 1024, 2048, vtb);
  attn_kernel<0><<<dim3(16, 64), 256, 0, stream>>>(
      q2b, 1024, kv2b, 2048, vtb, mask2, attnb);
  gemm_bt<1, 0, 0><<<dim3(32, 8), 256, 0, stream>>>(
      attnb, wt + 7 * W1M, bo2, bo2, bo2, bo2, c1f, nullptr, 4096, 1024, 1024);
  ln_kernel<1><<<4096, 256, 0, stream>>>(c1f, y1f, g2, be2, y2f, y2b);

  // ---- FFN
  gemm_bt<0, 1, 1><<<dim3(32, 32), 256, 0, stream>>>(
      y2b, wt + 8 * W1M, bff1, bff1 + 1024, bff1 + 2048, bff1 + 3072,
      nullptr, hb, 4096, 4096, 1024);
  gemm_bt<1, 0, 0><<<dim3(32, 8), 256, 0, stream>>>(
      hb, wt + 12 * W1M, bff2, bff2, bff2, bff2, c1f, nullptr, 4096, 1024, 4096);
  ln_kernel<0><<<4096, 256, 0, stream>>>(c1f, y2f, g3, be3, outf, nullptr);
}

// Round 3
// 424.430 us; speedup vs baseline: 1.2166x; 1.0582x over previous
//
#include <hip/hip_runtime.h>
#include <stdint.h>

typedef unsigned short ushort_t;
typedef __attribute__((ext_vector_type(8))) short bf16x8;   // 8 bf16 in 4 VGPRs
typedef __attribute__((ext_vector_type(4))) float f32x4;
typedef __attribute__((ext_vector_type(4))) unsigned short us4;

#define DEV __device__ __forceinline__

DEV unsigned short f2bf(float f) {           // RNE f32 -> bf16
  union { float f; unsigned u; } x; x.f = f;
  unsigned r = x.u + 0x7fffu + ((x.u >> 16) & 1u);
  return (unsigned short)(r >> 16);
}

DEV void gload16(const void* g, void* l) {   // async global->LDS, 16B/lane
  __builtin_amdgcn_global_load_lds(
      (const __attribute__((address_space(1))) unsigned int*)g,
      (__attribute__((address_space(3))) unsigned int*)l, 16, 0, 0);
}

// ---------------------------------------------------------------- casts
__global__ __launch_bounds__(256) void cast_bf16_kernel(
    const float* __restrict__ x, ushort_t* __restrict__ y, int n4) {
  int i = blockIdx.x * 256 + threadIdx.x;
  if (i >= n4) return;
  float4 v = ((const float4*)x)[i];
  us4 o; o.x = f2bf(v.x); o.y = f2bf(v.y); o.z = f2bf(v.z); o.w = f2bf(v.w);
  ((us4*)y)[i] = o;
}

// y[i] = bf16(p0[i] + p1[i])  (split-K reduce for Q2)
__global__ __launch_bounds__(256) void reduce_cast_kernel(
    const float* __restrict__ p0, const float* __restrict__ p1,
    ushort_t* __restrict__ y, int n4) {
  int i = blockIdx.x * 256 + threadIdx.x;
  if (i >= n4) return;
  float4 a = ((const float4*)p0)[i];
  float4 b = ((const float4*)p1)[i];
  us4 o; o.x = f2bf(a.x + b.x); o.y = f2bf(a.y + b.y);
  o.z = f2bf(a.z + b.z); o.w = f2bf(a.w + b.w);
  ((us4*)y)[i] = o;
}

// W[K,N] f32 -> Wt[N,K] bf16 (generic dims)
__global__ __launch_bounds__(256) void transpose_cast_kernel(
    const float* __restrict__ W, ushort_t* __restrict__ dst, int K, int N) {
  __shared__ float tile[64][65];
  int n0 = blockIdx.x * 64, k0 = blockIdx.y * 64;
  int tid = threadIdx.x;
#pragma unroll
  for (int it = 0; it < 16; ++it) {
    int idx = it * 256 + tid; int r = idx >> 6, c = idx & 63;
    tile[r][c] = W[(size_t)(k0 + r) * N + n0 + c];
  }
  __syncthreads();
#pragma unroll
  for (int it = 0; it < 16; ++it) {
    int idx = it * 256 + tid; int r = idx >> 6, c = idx & 63;
    dst[(size_t)(n0 + r) * K + k0 + c] = f2bf(tile[c][r]);
  }
}

struct Src8 { const float* p[8]; };
// 8x fused 1024x1024 weight transposes (one launch)
__global__ __launch_bounds__(256) void transpose_cast8_kernel(
    Src8 s, ushort_t* __restrict__ dst) {
  __shared__ float tile[64][65];
  const float* W = s.p[blockIdx.z];
  ushort_t* out = dst + (size_t)blockIdx.z * 1048576;
  int n0 = blockIdx.x * 64, k0 = blockIdx.y * 64;
  int tid = threadIdx.x;
#pragma unroll
  for (int it = 0; it < 16; ++it) {
    int idx = it * 256 + tid; int r = idx >> 6, c = idx & 63;
    tile[r][c] = W[(size_t)(k0 + r) * 1024 + n0 + c];
  }
  __syncthreads();
#pragma unroll
  for (int it = 0; it < 16; ++it) {
    int idx = it * 256 + tid; int r = idx >> 6, c = idx & 63;
    out[(size_t)(n0 + r) * 1024 + k0 + c] = f2bf(tile[c][r]);
  }
}

// V [B,S,(ldv)] head-cols -> vT [B*H, 64, 1024]   (us4-vectorized global I/O)
__global__ __launch_bounds__(256) void transpose_v_kernel(
    const ushort_t* __restrict__ V, int ldv, ushort_t* __restrict__ vT) {
  __shared__ ushort_t tile[64][65];
  int s0 = blockIdx.x * 64;
  int bh = blockIdx.y;
  int b = bh >> 4, h = bh & 15;
  int tid = threadIdx.x;
#pragma unroll
  for (int it = 0; it < 4; ++it) {
    int idx = it * 256 + tid; int r = idx >> 4, c = (idx & 15) * 4;
    us4 v = *(const us4*)&V[(size_t)(b * 1024 + s0 + r) * ldv + h * 64 + c];
    tile[r][c] = v.x; tile[r][c + 1] = v.y; tile[r][c + 2] = v.z; tile[r][c + 3] = v.w;
  }
  __syncthreads();
#pragma unroll
  for (int it = 0; it < 4; ++it) {
    int idx = it * 256 + tid; int r = idx >> 4, c = (idx & 15) * 4;
    us4 o; o.x = tile[c][r]; o.y = tile[c + 1][r]; o.z = tile[c + 2][r]; o.w = tile[c + 3][r];
    *(us4*)&vT[((size_t)bh * 64 + r) * 1024 + s0 + c] = o;
  }
}

// ---------------------------------------------------------------- GEMM
// C[M,N] = A[M,K](bf16) @ Bt[N,K]^T(bf16) + bias ; m97-style 128x128 tile.
// Split-K: block z covers K rows [z*Ks, (z+1)*Ks); f32 output goes to
// Cf + z*pstr; bias added only by z==0.
template <int WF32, int WB16, int RELU>
__global__ __launch_bounds__(256, 2) void gemm_bt(
    const ushort_t* __restrict__ A, const ushort_t* __restrict__ Bt,
    const float* __restrict__ b0, const float* __restrict__ b1,
    const float* __restrict__ b2, const float* __restrict__ b3,
    float* __restrict__ Cf, ushort_t* __restrict__ Cb,
    int M, int N, int K, int Ks, long long pstr) {
  __shared__ ushort_t sA[4096];  // [128][32] bf16, 8KB
  __shared__ ushort_t sB[4096];
  const int tid = threadIdx.x;
  const int w = tid >> 6, lane = tid & 63;
  const int lrow = lane & 15, lk = lane >> 4;
  const int m0 = blockIdx.x * 128, n0 = blockIdx.y * 128;
  const int kz = blockIdx.z * Ks;
  const int wr = w >> 1, wc = w & 1;
  f32x4 acc[4][4] = {};
  const int brow0 = (w * 1024 + lane * 16) >> 6;  // row for sweep 0
  const int kbyte = (lane * 16) & 63;             // byte within 64B row

  for (int kt = kz; kt < kz + Ks; kt += 32) {
    __syncthreads();
    const ushort_t* ga = A + (size_t)(m0 + brow0) * K + kt + (kbyte >> 1);
    gload16(ga, (char*)sA + w * 1024);
    gload16(ga + (size_t)64 * K, (char*)sA + 4096 + w * 1024);
    const ushort_t* gb = Bt + (size_t)(n0 + brow0) * K + kt + (kbyte >> 1);
    gload16(gb, (char*)sB + w * 1024);
    gload16(gb + (size_t)64 * K, (char*)sB + 4096 + w * 1024);
    __syncthreads();
    bf16x8 aF[4], bF[4];
#pragma unroll
    for (int t = 0; t < 4; ++t) {
      aF[t] = *(const bf16x8*)((const char*)sA + ((wr * 64 + t * 16 + lrow) << 6) + (lk << 4));
      bF[t] = *(const bf16x8*)((const char*)sB + ((wc * 64 + t * 16 + lrow) << 6) + (lk << 4));
    }
#pragma unroll
    for (int mt = 0; mt < 4; ++mt)
#pragma unroll
      for (int nt = 0; nt < 4; ++nt)
        acc[mt][nt] = __builtin_amdgcn_mfma_f32_16x16x32_bf16(aF[mt], bF[nt], acc[mt][nt], 0, 0, 0);
  }
  float* Cfz = Cf + (long long)blockIdx.z * pstr;
#pragma unroll
  for (int nt = 0; nt < 4; ++nt) {
    int col = n0 + wc * 64 + nt * 16 + lrow;
    int seg = col >> 10;
    const float* bp = seg == 0 ? b0 : seg == 1 ? b1 : seg == 2 ? b2 : b3;
    float bv = bp[col & 1023];
    if (blockIdx.z != 0) bv = 0.f;
#pragma unroll
    for (int mt = 0; mt < 4; ++mt) {
      int rowb = m0 + wr * 64 + mt * 16 + lk * 4;
#pragma unroll
      for (int j = 0; j < 4; ++j) {
        float v = acc[mt][nt][j] + bv;
        if (RELU) v = fmaxf(v, 0.f);
        size_t idx = (size_t)(rowb + j) * N + col;
        if (WF32) Cfz[idx] = v;
        if (WB16) Cb[idx] = f2bf(v);
      }
    }
  }
}

// ---------------------------------------------------------------- attention
// grid (S/64, B*H). 64 q rows/block, 4 waves x 16 rows. KVBLK=64,
// double-buffered K/V staging (T3 2-phase), XOR-swizzled LDS tiles.
template <int CAUSAL>
__global__ __launch_bounds__(256, 4) void attn_kernel(
    const ushort_t* __restrict__ Q, int ldq,
    const ushort_t* __restrict__ Kp, int ldk,
    const ushort_t* __restrict__ vT,  // [B*H,64,1024]
    const float* __restrict__ mask2,  // [B,1024] or null
    ushort_t* __restrict__ O) {       // [B*S,1024]
  __shared__ ushort_t sK[2][4096];    // [64 key][64 dh] swizzled, 8KB each
  __shared__ ushort_t sV[2][4096];    // [64 dh][64 key] swizzled
  __shared__ ushort_t sP[4][1024];    // per-wave [16 q][64 key] swizzled
  const int qb = blockIdx.x, bh = blockIdx.y;
  const int b = bh >> 4, h = bh & 15;
  const int tid = threadIdx.x, w = tid >> 6, lane = tid & 63;
  const int lrow = lane & 15, lk = lane >> 4;

  const ushort_t* qptr = Q + (size_t)(b * 1024 + qb * 64 + w * 16 + lrow) * ldq + h * 64 + lk * 8;
  bf16x8 qF0 = *(const bf16x8*)qptr;
  bf16x8 qF1 = *(const bf16x8*)(qptr + 32);
  f32x4 oacc[4] = {};
  float m_[4], l_[4];
#pragma unroll
  for (int j = 0; j < 4; ++j) { m_[j] = -3.0e38f; l_[j] = 0.f; }
  const int nkb = CAUSAL ? (qb + 1) : 16;
  const float C = 0.18033688011112042f;  // 0.125 * log2(e)

  const int sr = w * 16 + (lane >> 3);                  // row within 64
  const int scb = (((lane & 7) ^ (lane >> 3)) * 16);    // swizzled col byte
  const ushort_t* kbase = Kp + (size_t)(b * 1024 + sr) * ldk + h * 64 + (scb >> 1);
  const ushort_t* vbase = vT + ((size_t)bh * 64 + sr) * 1024 + (scb >> 1);
  char* dstK0 = (char*)sK[0] + w * 2048;  // HW adds lane*16
  char* dstV0 = (char*)sV[0] + w * 2048;

#define STAGE(kb_, bufi)                                              \
  do {                                                                \
    const ushort_t* gk = kbase + (size_t)(kb_) * 64 * ldk;            \
    gload16(gk, dstK0 + (bufi) * 8192);                               \
    gload16(gk + (size_t)8 * ldk, dstK0 + (bufi) * 8192 + 1024);      \
    const ushort_t* gv = vbase + (kb_) * 64;                          \
    gload16(gv, dstV0 + (bufi) * 8192);                               \
    gload16(gv + (size_t)8 * 1024, dstV0 + (bufi) * 8192 + 1024);     \
  } while (0)

  STAGE(0, 0);
  const int swz = (lrow & 7) << 4;

  for (int kb = 0; kb < nkb; ++kb) {
    const int buf = kb & 1;
    __syncthreads();                       // drains vmcnt: buf ready, buf^1 free
    if (kb + 1 < nkb) STAGE(kb + 1, buf ^ 1);

    const char* kB = (const char*)sK[buf];
    const char* vB = (const char*)sV[buf];
    // ---- QK^T (raw scores)
    f32x4 sc[4];
#pragma unroll
    for (int kt = 0; kt < 4; ++kt) {
      const char* rp = kB + ((kt * 16 + lrow) << 7);
      bf16x8 k0 = *(const bf16x8*)(rp + ((lk * 16) ^ swz));
      bf16x8 k1 = *(const bf16x8*)(rp + ((64 + lk * 16) ^ swz));
      f32x4 z = {};
      z = __builtin_amdgcn_mfma_f32_16x16x32_bf16(qF0, k0, z, 0, 0, 0);
      sc[kt] = __builtin_amdgcn_mfma_f32_16x16x32_bf16(qF1, k1, z, 0, 0, 0);
    }
    // ---- mask + online softmax (per q row j)
    float mv[4];
    if (!CAUSAL) {
#pragma unroll
      for (int kt = 0; kt < 4; ++kt)
        mv[kt] = mask2[b * 1024 + kb * 64 + kt * 16 + lrow];
    }
#pragma unroll
    for (int j = 0; j < 4; ++j) {
      float s0 = sc[0][j], s1 = sc[1][j], s2 = sc[2][j], s3 = sc[3][j];
      if (CAUSAL) {
        if (kb == qb) {
          int qr = w * 16 + lk * 4 + j;
          if (lrow > qr) s0 = -3.0e38f;
          if (16 + lrow > qr) s1 = -3.0e38f;
          if (32 + lrow > qr) s2 = -3.0e38f;
          if (48 + lrow > qr) s3 = -3.0e38f;
        }
      } else {
        s0 = fmaf(mv[0], -8e9f, s0);
        s1 = fmaf(mv[1], -8e9f, s1);
        s2 = fmaf(mv[2], -8e9f, s2);
        s3 = fmaf(mv[3], -8e9f, s3);
      }
      float mx = fmaxf(fmaxf(s0, s1), fmaxf(s2, s3));
      mx = fmaxf(mx, __shfl_xor(mx, 1));
      mx = fmaxf(mx, __shfl_xor(mx, 2));
      mx = fmaxf(mx, __shfl_xor(mx, 4));
      mx = fmaxf(mx, __shfl_xor(mx, 8));
      float mnew = fmaxf(m_[j], mx);
      float scale = __builtin_exp2f((m_[j] - mnew) * C);
      float e0 = __builtin_exp2f((s0 - mnew) * C);
      float e1 = __builtin_exp2f((s1 - mnew) * C);
      float e2 = __builtin_exp2f((s2 - mnew) * C);
      float e3 = __builtin_exp2f((s3 - mnew) * C);
      float ps = (e0 + e1) + (e2 + e3);
      ps += __shfl_xor(ps, 1);
      ps += __shfl_xor(ps, 2);
      ps += __shfl_xor(ps, 4);
      ps += __shfl_xor(ps, 8);
      l_[j] = l_[j] * scale + ps;
      m_[j] = mnew;
      oacc[0][j] *= scale; oacc[1][j] *= scale;
      oacc[2][j] *= scale; oacc[3][j] *= scale;
      int qp = lk * 4 + j;
      char* bp = (char*)sP[w] + qp * 128;
      int sz = (qp & 7) << 4;
      *(ushort_t*)(bp + ((lrow * 2) ^ sz)) = f2bf(e0);
      *(ushort_t*)(bp + ((32 + lrow * 2) ^ sz)) = f2bf(e1);
      *(ushort_t*)(bp + ((64 + lrow * 2) ^ sz)) = f2bf(e2);
      *(ushort_t*)(bp + ((96 + lrow * 2) ^ sz)) = f2bf(e3);
    }
    // ---- PV (wave-local dependency; compiler inserts lgkmcnt wait)
    const char* pB = (const char*)sP[w] + (lrow << 7);
    bf16x8 pF0 = *(const bf16x8*)(pB + ((lk * 16) ^ swz));
    bf16x8 pF1 = *(const bf16x8*)(pB + ((64 + lk * 16) ^ swz));
#pragma unroll
    for (int t = 0; t < 4; ++t) {
      const char* rp = vB + ((t * 16 + lrow) << 7);
      bf16x8 v0 = *(const bf16x8*)(rp + ((lk * 16) ^ swz));
      bf16x8 v1 = *(const bf16x8*)(rp + ((64 + lk * 16) ^ swz));
      oacc[t] = __builtin_amdgcn_mfma_f32_16x16x32_bf16(pF0, v0, oacc[t], 0, 0, 0);
      oacc[t] = __builtin_amdgcn_mfma_f32_16x16x32_bf16(pF1, v1, oacc[t], 0, 0, 0);
    }
  }
#undef STAGE
#pragma unroll
  for (int j = 0; j < 4; ++j) {
    float invl = 1.f / l_[j];
    int row = qb * 64 + w * 16 + lk * 4 + j;
    ushort_t* op = O + (size_t)(b * 1024 + row) * 1024 + h * 64;
#pragma unroll
    for (int t = 0; t < 4; ++t) op[t * 16 + lrow] = f2bf(oacc[t][j] * invl);
  }
}

// ---------------------------------------------------------------- layernorm
// y = LN(sum(partials) + r_row) * g + beta ; f32 out (+ optional bf16)
template <int WB16, int NPART>
__global__ __launch_bounds__(256) void ln_kernel(
    const float* __restrict__ p0, const float* __restrict__ p1,
    const float* __restrict__ p2, const float* __restrict__ p3,
    const float* __restrict__ r,
    const float* __restrict__ g, const float* __restrict__ be,
    float* __restrict__ yf, ushort_t* __restrict__ yb) {
  int row = blockIdx.x, tid = threadIdx.x;
  size_t off = (size_t)row * 1024;
  float4 va = ((const float4*)(p0 + off))[tid];
  if (NPART >= 2) {
    float4 t = ((const float4*)(p1 + off))[tid];
    va.x += t.x; va.y += t.y; va.z += t.z; va.w += t.w;
  }
  if (NPART >= 4) {
    float4 t2 = ((const float4*)(p2 + off))[tid];
    float4 t3 = ((const float4*)(p3 + off))[tid];
    va.x += t2.x + t3.x; va.y += t2.y + t3.y;
    va.z += t2.z + t3.z; va.w += t2.w + t3.w;
  }
  float4 vb = ((const float4*)(r + off))[tid];
  float x0 = va.x + vb.x, x1 = va.y + vb.y, x2 = va.z + vb.z, x3 = va.w + vb.w;
  float s = x0 + x1 + x2 + x3;
  float s2 = x0 * x0 + x1 * x1 + x2 * x2 + x3 * x3;
#pragma unroll
  for (int o = 1; o < 64; o <<= 1) { s += __shfl_xor(s, o); s2 += __shfl_xor(s2, o); }
  __shared__ float sh[8];
  if ((tid & 63) == 0) { sh[tid >> 6] = s; sh[4 + (tid >> 6)] = s2; }
  __syncthreads();
  s = sh[0] + sh[1] + sh[2] + sh[3];
  s2 = sh[4] + sh[5] + sh[6] + sh[7];
  float mu = s * 0.0009765625f;
  float var = s2 * 0.0009765625f - mu * mu;
  float inv = rsqrtf(var + 1e-6f);
  float4 gv = ((const float4*)g)[tid];
  float4 bv = ((const float4*)be)[tid];
  float y0 = (x0 - mu) * inv * gv.x + bv.x;
  float y1 = (x1 - mu) * inv * gv.y + bv.y;
  float y2 = (x2 - mu) * inv * gv.z + bv.z;
  float y3 = (x3 - mu) * inv * gv.w + bv.w;
  ((float4*)(yf + off))[tid] = make_float4(y0, y1, y2, y3);
  if (WB16) {
    us4 o; o.x = f2bf(y0); o.y = f2bf(y1); o.z = f2bf(y2); o.w = f2bf(y3);
    ((us4*)(yb + off))[tid] = o;
  }
}

// ---------------------------------------------------------------- launcher
extern "C" void kernel_launch(void* const* d_in, const int* in_sizes, int n_in,
                              void* d_out, int out_size, void* d_ws, size_t ws_size,
                              hipStream_t stream) {
  (void)in_sizes; (void)n_in; (void)out_size; (void)ws_size;
  const float* inputs = (const float*)d_in[0];
  const float* enc    = (const float*)d_in[1];
  const float* mask2  = (const float*)d_in[3];
  const float* wq1 = (const float*)d_in[4];  const float* bq1 = (const float*)d_in[5];
  const float* wk1 = (const float*)d_in[6];  const float* bk1 = (const float*)d_in[7];
  const float* wv1 = (const float*)d_in[8];  const float* bv1 = (const float*)d_in[9];
  const float* wo1 = (const float*)d_in[10]; const float* bo1 = (const float*)d_in[11];
  const float* wq2 = (const float*)d_in[12]; const float* bq2 = (const float*)d_in[13];
  const float* wk2 = (const float*)d_in[14]; const float* bk2 = (const float*)d_in[15];
  const float* wv2 = (const float*)d_in[16]; const float* bv2 = (const float*)d_in[17];
  const float* wo2 = (const float*)d_in[18]; const float* bo2 = (const float*)d_in[19];
  const float* wff1 = (const float*)d_in[20]; const float* bff1 = (const float*)d_in[21];
  const float* wff2 = (const float*)d_in[22]; const float* bff2 = (const float*)d_in[23];
  const float* g1 = (const float*)d_in[24]; const float* be1 = (const float*)d_in[25];
  const float* g2 = (const float*)d_in[26]; const float* be2 = (const float*)d_in[27];
  const float* g3 = (const float*)d_in[28]; const float* be3 = (const float*)d_in[29];

  char* ws = (char*)d_ws;
  const size_t MB = 1024 * 1024;
  const size_t W1M = 1048576;  // elements per 1024x1024 weight
  // --- workspace map (liveness verified per stream order) ---
  ushort_t* wt    = (ushort_t*)ws;              // 0..32MB  bf16 W^T (8x1MB elems + ff1t + ff2t)
  ushort_t* xb    = (ushort_t*)(ws + 32 * MB);  // 32..40   input bf16 (dead after QKV)
  ushort_t* encb  = (ushort_t*)(ws + 40 * MB);  // 40..48   enc bf16 (dead after KV2)
  ushort_t* qkvb  = (ushort_t*)(ws + 48 * MB);  // 48..72   QKV [4096][3072] (dead after attn1)
  ushort_t* vtb   = (ushort_t*)(ws + 72 * MB);  // 72..80   vT (per attention)
  ushort_t* attnb = (ushort_t*)(ws + 80 * MB);  // 80..88   attn out bf16
  ushort_t* y1b   = (ushort_t*)(ws + 88 * MB);  // 88..96   LN1 bf16 (dead after Q2)
  ushort_t* y2b   = (ushort_t*)(ws + 96 * MB);  // 96..104  LN2 bf16 (dead after FFN1)
  float*    c1f   = (float*)(ws + 104 * MB);    // 104..120 partial 0
  float*    p48f  = (float*)(ws + 48 * MB);     // alt partial 1 (overlays dead qkvb)
  float*    y1f   = (float*)(ws + 120 * MB);    // 120..136 LN1 f32 (dead after LN2)
  float*    y2f   = (float*)(ws + 136 * MB);    // 136..152 LN2 f32 (LN3 residual)
  ushort_t* q2b   = (ushort_t*)(ws + 32 * MB);  // 32..40   Q2 bf16 (overlays dead xb)
  ushort_t* kv2b  = (ushort_t*)(ws + 56 * MB);  // 56..72   KV2 (dead after attn2)
  ushort_t* hb    = (ushort_t*)(ws + 32 * MB);  // 32..64   FFN hidden (after attn2 done)
  float*    pff   = (float*)(ws + 72 * MB);     // 72..136  FF2 partials x4 (16MB apart)
  float* outf = (float*)d_out;
  const long long PELEMS = 4 * 1024 * 1024;          // 16MB of f32
  const long long P48OFF = (long long)(p48f - c1f);  // c1f -> p48f

  // prep: casts + weight transposes
  cast_bf16_kernel<<<4096, 256, 0, stream>>>(inputs, xb, 1048576);
  cast_bf16_kernel<<<4096, 256, 0, stream>>>(enc, encb, 1048576);
  Src8 s8; s8.p[0] = wq1; s8.p[1] = wk1; s8.p[2] = wv1; s8.p[3] = wo1;
           s8.p[4] = wq2; s8.p[5] = wk2; s8.p[6] = wv2; s8.p[7] = wo2;
  transpose_cast8_kernel<<<dim3(16, 16, 8), 256, 0, stream>>>(s8, wt);
  transpose_cast_kernel<<<dim3(64, 16), 256, 0, stream>>>(wff1, wt + 8 * W1M, 1024, 4096);
  transpose_cast_kernel<<<dim3(16, 64), 256, 0, stream>>>(wff2, wt + 12 * W1M, 4096, 1024);

  // ---- self-attention
  gemm_bt<0, 1, 0><<<dim3(32, 24, 1), 256, 0, stream>>>(
      xb, wt, bq1, bk1, bv1, bv1, nullptr, qkvb, 4096, 3072, 1024, 1024, 0);
  transpose_v_kernel<<<dim3(16, 64), 256, 0, stream>>>(qkvb + 2048, 3072, vtb);
  attn_kernel<1><<<dim3(16, 64), 256, 0, stream>>>(
      qkvb, 3072, qkvb + 1024, 3072, vtb, nullptr, attnb);
  gemm_bt<1, 0, 0><<<dim3(32, 8, 2), 256, 0, stream>>>(          // split-K=2
      attnb, wt + 3 * W1M, bo1, bo1, bo1, bo1, c1f, nullptr, 4096, 1024, 1024, 512, P48OFF);
  ln_kernel<1, 2><<<4096, 256, 0, stream>>>(c1f, p48f, nullptr, nullptr,
                                            inputs, g1, be1, y1f, y1b);

  // ---- cross-attention
  gemm_bt<1, 0, 0><<<dim3(32, 8, 2), 256, 0, stream>>>(          // Q2 split-K=2
      y1b, wt + 4 * W1M, bq2, bq2, bq2, bq2, c1f, nullptr, 4096, 1024, 1024, 512, P48OFF);
  reduce_cast_kernel<<<4096, 256, 0, stream>>>(c1f, p48f, q2b, 1048576);
  gemm_bt<0, 1, 0><<<dim3(32, 16, 1), 256, 0, stream>>>(
      encb, wt + 5 * W1M, bk2, bv2, bk2, bk2, nullptr, kv2b, 4096, 2048, 1024, 1024, 0);
  transpose_v_kernel<<<dim3(16, 64), 256, 0, stream>>>(kv2b + 1024, 2048, vtb);
  attn_kernel<0><<<dim3(16, 64), 256, 0, stream>>>(
      q2b, 1024, kv2b, 2048, vtb, mask2, attnb);
  gemm_bt<1, 0, 0><<<dim3(32, 8, 2), 256, 0, stream>>>(          // split-K=2
      attnb, wt + 7 * W1M, bo2, bo2, bo2, bo2, c1f, nullptr, 4096, 1024, 1024, 512, P48OFF);
  ln_kernel<1, 2><<<4096, 256, 0, stream>>>(c1f, p48f, nullptr, nullptr,
                                            y1f, g2, be2, y2f, y2b);

  // ---- FFN
  gemm_bt<0, 1, 1><<<dim3(32, 32, 1), 256, 0, stream>>>(
      y2b, wt + 8 * W1M, bff1, bff1 + 1024, bff1 + 2048, bff1 + 3072,
      nullptr, hb, 4096, 4096, 1024, 1024, 0);
  gemm_bt<1, 0, 0><<<dim3(32, 8, 4), 256, 0, stream>>>(          // FF2 split-K=4
      hb, wt + 12 * W1M, bff2, bff2, bff2, bff2, pff, nullptr,
      4096, 1024, 4096, 1024, PELEMS);
  ln_kernel<0, 4><<<4096, 256, 0, stream>>>(pff, pff + PELEMS, pff + 2 * PELEMS,
                                            pff + 3 * PELEMS, y2f, g3, be3, outf, nullptr);
}

// Round 4
// 373.089 us; speedup vs baseline: 1.3840x; 1.1376x over previous
//
#include <hip/hip_runtime.h>
#include <stdint.h>

typedef unsigned short ushort_t;
typedef __attribute__((ext_vector_type(8))) short bf16x8;   // 8 bf16 in 4 VGPRs
typedef __attribute__((ext_vector_type(4))) float f32x4;
typedef __attribute__((ext_vector_type(4))) unsigned short us4;

#define DEV __device__ __forceinline__

DEV unsigned short f2bf(float f) {           // RNE f32 -> bf16
  union { float f; unsigned u; } x; x.f = f;
  unsigned r = x.u + 0x7fffu + ((x.u >> 16) & 1u);
  return (unsigned short)(r >> 16);
}

DEV void gload16(const void* g, void* l) {   // async global->LDS, 16B/lane
  __builtin_amdgcn_global_load_lds(
      (const __attribute__((address_space(1))) unsigned int*)g,
      (__attribute__((address_space(3))) unsigned int*)l, 16, 0, 0);
}

// ---------------------------------------------------------------- casts
__global__ __launch_bounds__(256) void cast_bf16_kernel(
    const float* __restrict__ x, ushort_t* __restrict__ y, int n4) {
  int i = blockIdx.x * 256 + threadIdx.x;
  if (i >= n4) return;
  float4 v = ((const float4*)x)[i];
  us4 o; o.x = f2bf(v.x); o.y = f2bf(v.y); o.z = f2bf(v.z); o.w = f2bf(v.w);
  ((us4*)y)[i] = o;
}

// y[i] = bf16(p0[i] + p1[i])  (split-K reduce for Q2)
__global__ __launch_bounds__(256) void reduce_cast_kernel(
    const float* __restrict__ p0, const float* __restrict__ p1,
    ushort_t* __restrict__ y, int n4) {
  int i = blockIdx.x * 256 + threadIdx.x;
  if (i >= n4) return;
  float4 a = ((const float4*)p0)[i];
  float4 b = ((const float4*)p1)[i];
  us4 o; o.x = f2bf(a.x + b.x); o.y = f2bf(a.y + b.y);
  o.z = f2bf(a.z + b.z); o.w = f2bf(a.w + b.w);
  ((us4*)y)[i] = o;
}

// W[K,N] f32 -> Wt[N,K] bf16 (generic dims)
__global__ __launch_bounds__(256) void transpose_cast_kernel(
    const float* __restrict__ W, ushort_t* __restrict__ dst, int K, int N) {
  __shared__ float tile[64][65];
  int n0 = blockIdx.x * 64, k0 = blockIdx.y * 64;
  int tid = threadIdx.x;
#pragma unroll
  for (int it = 0; it < 16; ++it) {
    int idx = it * 256 + tid; int r = idx >> 6, c = idx & 63;
    tile[r][c] = W[(size_t)(k0 + r) * N + n0 + c];
  }
  __syncthreads();
#pragma unroll
  for (int it = 0; it < 16; ++it) {
    int idx = it * 256 + tid; int r = idx >> 6, c = idx & 63;
    dst[(size_t)(n0 + r) * K + k0 + c] = f2bf(tile[c][r]);
  }
}

struct Src8 { const float* p[8]; };
// 8x fused 1024x1024 weight transposes (one launch)
__global__ __launch_bounds__(256) void transpose_cast8_kernel(
    Src8 s, ushort_t* __restrict__ dst) {
  __shared__ float tile[64][65];
  const float* W = s.p[blockIdx.z];
  ushort_t* out = dst + (size_t)blockIdx.z * 1048576;
  int n0 = blockIdx.x * 64, k0 = blockIdx.y * 64;
  int tid = threadIdx.x;
#pragma unroll
  for (int it = 0; it < 16; ++it) {
    int idx = it * 256 + tid; int r = idx >> 6, c = idx & 63;
    tile[r][c] = W[(size_t)(k0 + r) * 1024 + n0 + c];
  }
  __syncthreads();
#pragma unroll
  for (int it = 0; it < 16; ++it) {
    int idx = it * 256 + tid; int r = idx >> 6, c = idx & 63;
    out[(size_t)(n0 + r) * 1024 + k0 + c] = f2bf(tile[c][r]);
  }
}

// V [B,S,(ldv)] head-cols -> vT [B*H, 64, 1024]   (us4-vectorized global I/O)
__global__ __launch_bounds__(256) void transpose_v_kernel(
    const ushort_t* __restrict__ V, int ldv, ushort_t* __restrict__ vT) {
  __shared__ ushort_t tile[64][65];
  int s0 = blockIdx.x * 64;
  int bh = blockIdx.y;
  int b = bh >> 4, h = bh & 15;
  int tid = threadIdx.x;
#pragma unroll
  for (int it = 0; it < 4; ++it) {
    int idx = it * 256 + tid; int r = idx >> 4, c = (idx & 15) * 4;
    us4 v = *(const us4*)&V[(size_t)(b * 1024 + s0 + r) * ldv + h * 64 + c];
    tile[r][c] = v.x; tile[r][c + 1] = v.y; tile[r][c + 2] = v.z; tile[r][c + 3] = v.w;
  }
  __syncthreads();
#pragma unroll
  for (int it = 0; it < 4; ++it) {
    int idx = it * 256 + tid; int r = idx >> 4, c = (idx & 15) * 4;
    us4 o; o.x = tile[c][r]; o.y = tile[c + 1][r]; o.z = tile[c + 2][r]; o.w = tile[c + 3][r];
    *(us4*)&vT[((size_t)bh * 64 + r) * 1024 + s0 + c] = o;
  }
}

// ---------------------------------------------------------------- GEMM
// C[M,N] = A[M,K](bf16) @ Bt[N,K]^T(bf16) + bias ; m97-style 128x128 tile.
// Split-K: block z covers K rows [z*Ks, (z+1)*Ks); f32 output goes to
// Cf + z*pstr; bias added only by z==0.
template <int WF32, int WB16, int RELU>
__global__ __launch_bounds__(256, 2) void gemm_bt(
    const ushort_t* __restrict__ A, const ushort_t* __restrict__ Bt,
    const float* __restrict__ b0, const float* __restrict__ b1,
    const float* __restrict__ b2, const float* __restrict__ b3,
    float* __restrict__ Cf, ushort_t* __restrict__ Cb,
    int M, int N, int K, int Ks, long long pstr) {
  __shared__ ushort_t sA[4096];  // [128][32] bf16, 8KB
  __shared__ ushort_t sB[4096];
  const int tid = threadIdx.x;
  const int w = tid >> 6, lane = tid & 63;
  const int lrow = lane & 15, lk = lane >> 4;
  const int m0 = blockIdx.x * 128, n0 = blockIdx.y * 128;
  const int kz = blockIdx.z * Ks;
  const int wr = w >> 1, wc = w & 1;
  f32x4 acc[4][4] = {};
  const int brow0 = (w * 1024 + lane * 16) >> 6;  // row for sweep 0
  const int kbyte = (lane * 16) & 63;             // byte within 64B row

  for (int kt = kz; kt < kz + Ks; kt += 32) {
    __syncthreads();
    const ushort_t* ga = A + (size_t)(m0 + brow0) * K + kt + (kbyte >> 1);
    gload16(ga, (char*)sA + w * 1024);
    gload16(ga + (size_t)64 * K, (char*)sA + 4096 + w * 1024);
    const ushort_t* gb = Bt + (size_t)(n0 + brow0) * K + kt + (kbyte >> 1);
    gload16(gb, (char*)sB + w * 1024);
    gload16(gb + (size_t)64 * K, (char*)sB + 4096 + w * 1024);
    __syncthreads();
    bf16x8 aF[4], bF[4];
#pragma unroll
    for (int t = 0; t < 4; ++t) {
      aF[t] = *(const bf16x8*)((const char*)sA + ((wr * 64 + t * 16 + lrow) << 6) + (lk << 4));
      bF[t] = *(const bf16x8*)((const char*)sB + ((wc * 64 + t * 16 + lrow) << 6) + (lk << 4));
    }
#pragma unroll
    for (int mt = 0; mt < 4; ++mt)
#pragma unroll
      for (int nt = 0; nt < 4; ++nt)
        acc[mt][nt] = __builtin_amdgcn_mfma_f32_16x16x32_bf16(aF[mt], bF[nt], acc[mt][nt], 0, 0, 0);
  }
  float* Cfz = Cf + (long long)blockIdx.z * pstr;
#pragma unroll
  for (int nt = 0; nt < 4; ++nt) {
    int col = n0 + wc * 64 + nt * 16 + lrow;
    int seg = col >> 10;
    const float* bp = seg == 0 ? b0 : seg == 1 ? b1 : seg == 2 ? b2 : b3;
    float bv = bp[col & 1023];
    if (blockIdx.z != 0) bv = 0.f;
#pragma unroll
    for (int mt = 0; mt < 4; ++mt) {
      int rowb = m0 + wr * 64 + mt * 16 + lk * 4;
#pragma unroll
      for (int j = 0; j < 4; ++j) {
        float v = acc[mt][nt][j] + bv;
        if (RELU) v = fmaxf(v, 0.f);
        size_t idx = (size_t)(rowb + j) * N + col;
        if (WF32) Cfz[idx] = v;
        if (WB16) Cb[idx] = f2bf(v);
      }
    }
  }
}

// ---------------------------------------------------------------- attention
// grid (B*H, S/64). 64 q rows/block, 4 waves x 16 rows. KVBLK=64,
// double-buffered K/V staging, XOR-swizzled LDS. SWAPPED QK^T (T12-style):
// mfma(K,Q) puts a full key-slice per lane (q = lane&15) -> lane-local
// softmax reduce + 2 shfl. P packed via v_cvt_pk_bf16_f32 -> ds_write_b64.
template <int CAUSAL>
__global__ __launch_bounds__(256, 4) void attn_kernel(
    const ushort_t* __restrict__ Q, int ldq,
    const ushort_t* __restrict__ Kp, int ldk,
    const ushort_t* __restrict__ vT,  // [B*H,64,1024]
    const float* __restrict__ mask2,  // [B,1024] or null
    ushort_t* __restrict__ O) {       // [B*S,1024]
  __shared__ ushort_t sK[2][4096];    // [64 key][64 dh] swizzled, 8KB each
  __shared__ ushort_t sV[2][4096];    // [64 dh][64 key] swizzled
  __shared__ ushort_t sP[4][1024];    // per-wave [16 q][64 key] swizzled
  const int bh = blockIdx.x, qb = blockIdx.y;
  const int b = bh >> 4, h = bh & 15;
  const int tid = threadIdx.x, w = tid >> 6, lane = tid & 63;
  const int lrow = lane & 15, lk = lane >> 4;

  const ushort_t* qptr = Q + (size_t)(b * 1024 + qb * 64 + w * 16 + lrow) * ldq + h * 64 + lk * 8;
  bf16x8 qF0 = *(const bf16x8*)qptr;
  bf16x8 qF1 = *(const bf16x8*)(qptr + 32);
  f32x4 oacc[4] = {};                 // [t][j]: q=lk*4+j, d=t*16+lrow
  float m_ = -3.0e38f, l_ = 0.f;      // per-lane state for q = lrow
  const int nkb = CAUSAL ? (qb + 1) : 16;
  const float C = 0.18033688011112042f;  // 0.125 * log2(e)

  const int sr = w * 16 + (lane >> 3);                  // row within 64
  const int scb = (((lane & 7) ^ (lane >> 3)) * 16);    // swizzled col byte
  const ushort_t* kbase = Kp + (size_t)(b * 1024 + sr) * ldk + h * 64 + (scb >> 1);
  const ushort_t* vbase = vT + ((size_t)bh * 64 + sr) * 1024 + (scb >> 1);
  char* dstK0 = (char*)sK[0] + w * 2048;  // HW adds lane*16
  char* dstV0 = (char*)sV[0] + w * 2048;

#define STAGE(kb_, bufi)                                              \
  do {                                                                \
    const ushort_t* gk = kbase + (size_t)(kb_) * 64 * ldk;            \
    gload16(gk, dstK0 + (bufi) * 8192);                               \
    gload16(gk + (size_t)8 * ldk, dstK0 + (bufi) * 8192 + 1024);      \
    const ushort_t* gv = vbase + (kb_) * 64;                          \
    gload16(gv, dstV0 + (bufi) * 8192);                               \
    gload16(gv + (size_t)8 * 1024, dstV0 + (bufi) * 8192 + 1024);     \
  } while (0)

  STAGE(0, 0);
  const int swz = (lrow & 7) << 4;

  for (int kb = 0; kb < nkb; ++kb) {
    const int buf = kb & 1;
    __syncthreads();                       // drains vmcnt: buf ready, buf^1 free
    if (kb + 1 < nkb) STAGE(kb + 1, buf ^ 1);

    const char* kB = (const char*)sK[buf];
    const char* vB = (const char*)sV[buf];
    // ---- QK^T swapped: sc[kt][j] = S[key = kt*16+lk*4+j][q = lrow]
    f32x4 sc[4];
    __builtin_amdgcn_s_setprio(1);
#pragma unroll
    for (int kt = 0; kt < 4; ++kt) {
      const char* rp = kB + ((kt * 16 + lrow) << 7);
      bf16x8 k0 = *(const bf16x8*)(rp + ((lk * 16) ^ swz));
      bf16x8 k1 = *(const bf16x8*)(rp + ((64 + lk * 16) ^ swz));
      f32x4 z = {};
      z = __builtin_amdgcn_mfma_f32_16x16x32_bf16(k0, qF0, z, 0, 0, 0);
      sc[kt] = __builtin_amdgcn_mfma_f32_16x16x32_bf16(k1, qF1, sc[kt] = z, 0, 0, 0);
    }
    __builtin_amdgcn_s_setprio(0);
    // ---- mask
    if (CAUSAL) {
      if (kb == qb) {
        int ql = w * 16 + lrow;
#pragma unroll
        for (int kt = 0; kt < 4; ++kt)
#pragma unroll
          for (int j = 0; j < 4; ++j)
            if (kt * 16 + lk * 4 + j > ql) sc[kt][j] = -3.0e38f;
      }
    } else {
#pragma unroll
      for (int kt = 0; kt < 4; ++kt) {
        float4 mv = *(const float4*)&mask2[b * 1024 + kb * 64 + kt * 16 + lk * 4];
        sc[kt][0] = fmaf(mv.x, -8e9f, sc[kt][0]);
        sc[kt][1] = fmaf(mv.y, -8e9f, sc[kt][1]);
        sc[kt][2] = fmaf(mv.z, -8e9f, sc[kt][2]);
        sc[kt][3] = fmaf(mv.w, -8e9f, sc[kt][3]);
      }
    }
    // ---- online softmax: lane-local tree + 2 shfl
    float mx = fmaxf(fmaxf(fmaxf(sc[0][0], sc[0][1]), fmaxf(sc[0][2], sc[0][3])),
                     fmaxf(fmaxf(sc[1][0], sc[1][1]), fmaxf(sc[1][2], sc[1][3])));
    mx = fmaxf(mx, fmaxf(fmaxf(fmaxf(sc[2][0], sc[2][1]), fmaxf(sc[2][2], sc[2][3])),
                         fmaxf(fmaxf(sc[3][0], sc[3][1]), fmaxf(sc[3][2], sc[3][3]))));
    mx = fmaxf(mx, __shfl_xor(mx, 16));
    mx = fmaxf(mx, __shfl_xor(mx, 32));
    float mnew = fmaxf(m_, mx);
    float scale = __builtin_exp2f((m_ - mnew) * C);
    float ps = 0.f;
#pragma unroll
    for (int kt = 0; kt < 4; ++kt)
#pragma unroll
      for (int j = 0; j < 4; ++j) {
        float e = __builtin_exp2f((sc[kt][j] - mnew) * C);
        sc[kt][j] = e;
        ps += e;
      }
    ps += __shfl_xor(ps, 16);
    ps += __shfl_xor(ps, 32);
    l_ = l_ * scale + ps;
    m_ = mnew;
    if (__any(scale < 1.f)) {              // defer: skip rescale when max unchanged
#pragma unroll
      for (int j = 0; j < 4; ++j) {
        float sj = __shfl(scale, lk * 4 + j);
        oacc[0][j] *= sj; oacc[1][j] *= sj; oacc[2][j] *= sj; oacc[3][j] *= sj;
      }
    }
    // ---- pack P (cvt_pk) + ds_write_b64, swizzled by q row
    char* bp = (char*)sP[w] + lrow * 128;
#pragma unroll
    for (int kt = 0; kt < 4; ++kt) {
      unsigned d0, d1;
      asm("v_cvt_pk_bf16_f32 %0, %1, %2" : "=v"(d0) : "v"(sc[kt][0]), "v"(sc[kt][1]));
      asm("v_cvt_pk_bf16_f32 %0, %1, %2" : "=v"(d1) : "v"(sc[kt][2]), "v"(sc[kt][3]));
      uint2 dd; dd.x = d0; dd.y = d1;
      *(uint2*)(bp + ((kt * 32 + lk * 8) ^ swz)) = dd;
    }
    // ---- PV (wave-local dependency; compiler inserts lgkmcnt wait)
    bf16x8 pF0 = *(const bf16x8*)(bp + ((lk * 16) ^ swz));
    bf16x8 pF1 = *(const bf16x8*)(bp + ((64 + lk * 16) ^ swz));
    __builtin_amdgcn_s_setprio(1);
#pragma unroll
    for (int t = 0; t < 4; ++t) {
      const char* rp = vB + ((t * 16 + lrow) << 7);
      bf16x8 v0 = *(const bf16x8*)(rp + ((lk * 16) ^ swz));
      bf16x8 v1 = *(const bf16x8*)(rp + ((64 + lk * 16) ^ swz));
      oacc[t] = __builtin_amdgcn_mfma_f32_16x16x32_bf16(pF0, v0, oacc[t], 0, 0, 0);
      oacc[t] = __builtin_amdgcn_mfma_f32_16x16x32_bf16(pF1, v1, oacc[t], 0, 0, 0);
    }
    __builtin_amdgcn_s_setprio(0);
  }
#undef STAGE
#pragma unroll
  for (int j = 0; j < 4; ++j) {
    float lj = __shfl(l_, lk * 4 + j);
    float invl = 1.f / lj;
    int row = qb * 64 + w * 16 + lk * 4 + j;
    ushort_t* op = O + (size_t)(b * 1024 + row) * 1024 + h * 64;
#pragma unroll
    for (int t = 0; t < 4; ++t) op[t * 16 + lrow] = f2bf(oacc[t][j] * invl);
  }
}

// ---------------------------------------------------------------- layernorm
// y = LN(sum(partials) + r_row) * g + beta ; f32 out (+ optional bf16)
template <int WB16, int NPART>
__global__ __launch_bounds__(256) void ln_kernel(
    const float* __restrict__ p0, const float* __restrict__ p1,
    const float* __restrict__ p2, const float* __restrict__ p3,
    const float* __restrict__ r,
    const float* __restrict__ g, const float* __restrict__ be,
    float* __restrict__ yf, ushort_t* __restrict__ yb) {
  int row = blockIdx.x, tid = threadIdx.x;
  size_t off = (size_t)row * 1024;
  float4 va = ((const float4*)(p0 + off))[tid];
  if (NPART >= 2) {
    float4 t = ((const float4*)(p1 + off))[tid];
    va.x += t.x; va.y += t.y; va.z += t.z; va.w += t.w;
  }
  if (NPART >= 4) {
    float4 t2 = ((const float4*)(p2 + off))[tid];
    float4 t3 = ((const float4*)(p3 + off))[tid];
    va.x += t2.x + t3.x; va.y += t2.y + t3.y;
    va.z += t2.z + t3.z; va.w += t2.w + t3.w;
  }
  float4 vb = ((const float4*)(r + off))[tid];
  float x0 = va.x + vb.x, x1 = va.y + vb.y, x2 = va.z + vb.z, x3 = va.w + vb.w;
  float s = x0 + x1 + x2 + x3;
  float s2 = x0 * x0 + x1 * x1 + x2 * x2 + x3 * x3;
#pragma unroll
  for (int o = 1; o < 64; o <<= 1) { s += __shfl_xor(s, o); s2 += __shfl_xor(s2, o); }
  __shared__ float sh[8];
  if ((tid & 63) == 0) { sh[tid >> 6] = s; sh[4 + (tid >> 6)] = s2; }
  __syncthreads();
  s = sh[0] + sh[1] + sh[2] + sh[3];
  s2 = sh[4] + sh[5] + sh[6] + sh[7];
  float mu = s * 0.0009765625f;
  float var = s2 * 0.0009765625f - mu * mu;
  float inv = rsqrtf(var + 1e-6f);
  float4 gv = ((const float4*)g)[tid];
  float4 bv = ((const float4*)be)[tid];
  float y0 = (x0 - mu) * inv * gv.x + bv.x;
  float y1 = (x1 - mu) * inv * gv.y + bv.y;
  float y2 = (x2 - mu) * inv * gv.z + bv.z;
  float y3 = (x3 - mu) * inv * gv.w + bv.w;
  ((float4*)(yf + off))[tid] = make_float4(y0, y1, y2, y3);
  if (WB16) {
    us4 o; o.x = f2bf(y0); o.y = f2bf(y1); o.z = f2bf(y2); o.w = f2bf(y3);
    ((us4*)(yb + off))[tid] = o;
  }
}

// ---------------------------------------------------------------- launcher
extern "C" void kernel_launch(void* const* d_in, const int* in_sizes, int n_in,
                              void* d_out, int out_size, void* d_ws, size_t ws_size,
                              hipStream_t stream) {
  (void)in_sizes; (void)n_in; (void)out_size; (void)ws_size;
  const float* inputs = (const float*)d_in[0];
  const float* enc    = (const float*)d_in[1];
  const float* mask2  = (const float*)d_in[3];
  const float* wq1 = (const float*)d_in[4];  const float* bq1 = (const float*)d_in[5];
  const float* wk1 = (const float*)d_in[6];  const float* bk1 = (const float*)d_in[7];
  const float* wv1 = (const float*)d_in[8];  const float* bv1 = (const float*)d_in[9];
  const float* wo1 = (const float*)d_in[10]; const float* bo1 = (const float*)d_in[11];
  const float* wq2 = (const float*)d_in[12]; const float* bq2 = (const float*)d_in[13];
  const float* wk2 = (const float*)d_in[14]; const float* bk2 = (const float*)d_in[15];
  const float* wv2 = (const float*)d_in[16]; const float* bv2 = (const float*)d_in[17];
  const float* wo2 = (const float*)d_in[18]; const float* bo2 = (const float*)d_in[19];
  const float* wff1 = (const float*)d_in[20]; const float* bff1 = (const float*)d_in[21];
  const float* wff2 = (const float*)d_in[22]; const float* bff2 = (const float*)d_in[23];
  const float* g1 = (const float*)d_in[24]; const float* be1 = (const float*)d_in[25];
  const float* g2 = (const float*)d_in[26]; const float* be2 = (const float*)d_in[27];
  const float* g3 = (const float*)d_in[28]; const float* be3 = (const float*)d_in[29];

  char* ws = (char*)d_ws;
  const size_t MB = 1024 * 1024;
  const size_t W1M = 1048576;  // elements per 1024x1024 weight
  // --- workspace map (liveness verified per stream order) ---
  ushort_t* wt    = (ushort_t*)ws;              // 0..32MB  bf16 W^T (8x1MB elems + ff1t + ff2t)
  ushort_t* xb    = (ushort_t*)(ws + 32 * MB);  // 32..40   input bf16 (dead after QKV)
  ushort_t* encb  = (ushort_t*)(ws + 40 * MB);  // 40..48   enc bf16 (dead after KV2)
  ushort_t* qkvb  = (ushort_t*)(ws + 48 * MB);  // 48..72   QKV [4096][3072] (dead after attn1)
  ushort_t* vtb   = (ushort_t*)(ws + 72 * MB);  // 72..80   vT (per attention)
  ushort_t* attnb = (ushort_t*)(ws + 80 * MB);  // 80..88   attn out bf16
  ushort_t* y1b   = (ushort_t*)(ws + 88 * MB);  // 88..96   LN1 bf16 (dead after Q2)
  ushort_t* y2b   = (ushort_t*)(ws + 96 * MB);  // 96..104  LN2 bf16 (dead after FFN1)
  float*    c1f   = (float*)(ws + 104 * MB);    // 104..120 partial 0
  float*    p48f  = (float*)(ws + 48 * MB);     // alt partial 1 (overlays dead qkvb)
  float*    y1f   = (float*)(ws + 120 * MB);    // 120..136 LN1 f32 (dead after LN2)
  float*    y2f   = (float*)(ws + 136 * MB);    // 136..152 LN2 f32 (LN3 residual)
  ushort_t* q2b   = (ushort_t*)(ws + 32 * MB);  // 32..40   Q2 bf16 (overlays dead xb)
  ushort_t* kv2b  = (ushort_t*)(ws + 56 * MB);  // 56..72   KV2 (dead after attn2)
  ushort_t* hb    = (ushort_t*)(ws + 32 * MB);  // 32..64   FFN hidden (after attn2 done)
  float*    pff   = (float*)(ws + 72 * MB);     // 72..136  FF2 partials x4 (16MB apart)
  float* outf = (float*)d_out;
  const long long PELEMS = 4 * 1024 * 1024;          // 16MB of f32
  const long long P48OFF = (long long)(p48f - c1f);  // c1f -> p48f

  // prep: casts + weight transposes
  cast_bf16_kernel<<<4096, 256, 0, stream>>>(inputs, xb, 1048576);
  cast_bf16_kernel<<<4096, 256, 0, stream>>>(enc, encb, 1048576);
  Src8 s8; s8.p[0] = wq1; s8.p[1] = wk1; s8.p[2] = wv1; s8.p[3] = wo1;
           s8.p[4] = wq2; s8.p[5] = wk2; s8.p[6] = wv2; s8.p[7] = wo2;
  transpose_cast8_kernel<<<dim3(16, 16, 8), 256, 0, stream>>>(s8, wt);
  transpose_cast_kernel<<<dim3(64, 16), 256, 0, stream>>>(wff1, wt + 8 * W1M, 1024, 4096);
  transpose_cast_kernel<<<dim3(16, 64), 256, 0, stream>>>(wff2, wt + 12 * W1M, 4096, 1024);

  // ---- self-attention
  gemm_bt<0, 1, 0><<<dim3(32, 24, 1), 256, 0, stream>>>(
      xb, wt, bq1, bk1, bv1, bv1, nullptr, qkvb, 4096, 3072, 1024, 1024, 0);
  transpose_v_kernel<<<dim3(16, 64), 256, 0, stream>>>(qkvb + 2048, 3072, vtb);
  attn_kernel<1><<<dim3(64, 16), 256, 0, stream>>>(
      qkvb, 3072, qkvb + 1024, 3072, vtb, nullptr, attnb);
  gemm_bt<1, 0, 0><<<dim3(32, 8, 2), 256, 0, stream>>>(          // split-K=2
      attnb, wt + 3 * W1M, bo1, bo1, bo1, bo1, c1f, nullptr, 4096, 1024, 1024, 512, P48OFF);
  ln_kernel<1, 2><<<4096, 256, 0, stream>>>(c1f, p48f, nullptr, nullptr,
                                            inputs, g1, be1, y1f, y1b);

  // ---- cross-attention
  gemm_bt<1, 0, 0><<<dim3(32, 8, 2), 256, 0, stream>>>(          // Q2 split-K=2
      y1b, wt + 4 * W1M, bq2, bq2, bq2, bq2, c1f, nullptr, 4096, 1024, 1024, 512, P48OFF);
  reduce_cast_kernel<<<4096, 256, 0, stream>>>(c1f, p48f, q2b, 1048576);
  gemm_bt<0, 1, 0><<<dim3(32, 16, 1), 256, 0, stream>>>(
      encb, wt + 5 * W1M, bk2, bv2, bk2, bk2, nullptr, kv2b, 4096, 2048, 1024, 1024, 0);
  transpose_v_kernel<<<dim3(16, 64), 256, 0, stream>>>(kv2b + 1024, 2048, vtb);
  attn_kernel<0><<<dim3(64, 16), 256, 0, stream>>>(
      q2b, 1024, kv2b, 2048, vtb, mask2, attnb);
  gemm_bt<1, 0, 0><<<dim3(32, 8, 2), 256, 0, stream>>>(          // split-K=2
      attnb, wt + 7 * W1M, bo2, bo2, bo2, bo2, c1f, nullptr, 4096, 1024, 1024, 512, P48OFF);
  ln_kernel<1, 2><<<4096, 256, 0, stream>>>(c1f, p48f, nullptr, nullptr,
                                            y1f, g2, be2, y2f, y2b);

  // ---- FFN
  gemm_bt<0, 1, 1><<<dim3(32, 32, 1), 256, 0, stream>>>(
      y2b, wt + 8 * W1M, bff1, bff1 + 1024, bff1 + 2048, bff1 + 3072,
      nullptr, hb, 4096, 4096, 1024, 1024, 0);
  gemm_bt<1, 0, 0><<<dim3(32, 8, 4), 256, 0, stream>>>(          // FF2 split-K=4
      hb, wt + 12 * W1M, bff2, bff2, bff2, bff2, pff, nullptr,
      4096, 1024, 4096, 1024, PELEMS);
  ln_kernel<0, 4><<<4096, 256, 0, stream>>>(pff, pff + PELEMS, pff + 2 * PELEMS,
                                            pff + 3 * PELEMS, y2f, g3, be3, outf, nullptr);
}